// Round 3
// baseline (5164.123 us; speedup 1.0000x reference)
//
#include <hip/hip_runtime.h>
#include <math.h>

#define NXY 513
#define NIN 511
#define NL3 3
#define NE4 4
#define NB 12
#define GLD 512

static constexpr long FS  = (long)NE4 * NL3 * NXY * NXY;   // 3,158,028 floats
static constexpr long GSZ = (long)NB * GLD * GLD;          // 3,145,728 elements
static constexpr int  NSTEPS = 4;

static constexpr double dF0 = 9.375e-05;
static constexpr double dDX = 10000.0;
static constexpr float ZFBCf     = (float)(0.2 / (1.0 + 0.5 * 0.2));
static constexpr float JACCf     = (float)(1.0 / (dF0 * dDX * dDX));
static constexpr float HYPCf     = (float)(2.0e9 / (dF0 * dF0) / (dDX*dDX*dDX*dDX*dDX*dDX));
static constexpr float BFCf      = (float)(2.0 / (2.0 * dF0 * dDX * dDX * (-2900.0)));
static constexpr float INVF0DX2f = (float)(1.0 / ((dF0 * dDX) * (dF0 * dDX)));

typedef short  bf16x8 __attribute__((ext_vector_type(8)));
typedef float  f32x4  __attribute__((ext_vector_type(4)));

__device__ __forceinline__ unsigned short f2bf(float x) {
    unsigned int u = __float_as_uint(x);
    return (unsigned short)((u + 0x7FFFu + ((u >> 16) & 1u)) >> 16);
}
__device__ __forceinline__ float bf2f(unsigned short h) {
    return __uint_as_float(((unsigned int)h) << 16);
}

// ---------------- DST matrix (bf16 hi/lo): S[n][k] = (1/16) sin(pi (n+1)(k+1)/512), zero-padded --
__global__ void initS_kernel(unsigned short* __restrict__ Sh, unsigned short* __restrict__ Sl) {
    int k = blockIdx.x * 256 + threadIdx.x;
    int n = blockIdx.y;
    if (k >= GLD || n >= GLD) return;
    float v = 0.f;
    if (n < NIN && k < NIN) {
        int m = ((n + 1) * (k + 1)) & 1023;
        v = (float)(0.0625 * sin(M_PI * (double)m / 512.0));
    }
    unsigned short hs = f2bf(v);
    Sh[n * GLD + k] = hs;
    Sl[n * GLD + k] = f2bf(v - bf2f(hs));
}

// ---------------- fused lap(lap_bc(lap_bc(p))) + jacobian + wind + friction --------------------
// One block = one (e,l) plane, 16(x) x 64(y) interior outputs, 3-halo staged in LDS.
__global__ __launch_bounds__(256) void fused_rhs(
    float* __restrict__ kq, const float* __restrict__ q, const float* __restrict__ p,
    const float* __restrict__ wind)
{
    __shared__ float ps[22][72];
    __shared__ float qs[22][72];
    __shared__ float l1[22][72];
    __shared__ float l2[22][72];
    const int c  = blockIdx.z;
    const int x0 = 1 + blockIdx.y * 16;
    const int y0 = 1 + blockIdx.x * 64;
    const int t  = threadIdx.x;
    const size_t off = (size_t)c * NXY * NXY;
    const float* pp = p + off;
    const float* qp = q + off;

    for (int idx = t; idx < 22 * 70; idx += 256) {
        int i = idx / 70, j = idx % 70;
        int gx = x0 - 3 + i, gy = y0 - 3 + j;
        bool in = (gx >= 0 && gx < NXY && gy >= 0 && gy < NXY);
        size_t go = (size_t)gx * NXY + gy;
        ps[i][j] = in ? pp[go] : 0.f;
        qs[i][j] = in ? qp[go] : 0.f;
    }
    __syncthreads();

#define LAPBC(a, i, j, gx, gy) \
    ((gy) == 0       ? ZFBCf * (a[i][(j)+1] - a[i][j]) : \
     (gy) == NXY-1   ? ZFBCf * (a[i][(j)-1] - a[i][j]) : \
     (gx) == 0       ? ZFBCf * (a[(i)+1][j] - a[i][j]) : \
     (gx) == NXY-1   ? ZFBCf * (a[(i)-1][j] - a[i][j]) : \
     a[(i)+1][j] + a[(i)-1][j] + a[i][(j)+1] + a[i][(j)-1] - 4.f * a[i][j])

    for (int idx = t; idx < 20 * 68; idx += 256) {
        int i = 1 + idx / 68, j = 1 + idx % 68;
        int gx = x0 - 3 + i, gy = y0 - 3 + j;
        float v = 0.f;
        if (gx >= 0 && gx < NXY && gy >= 0 && gy < NXY) v = LAPBC(ps, i, j, gx, gy);
        l1[i][j] = v;
    }
    __syncthreads();

    for (int idx = t; idx < 18 * 66; idx += 256) {
        int i = 2 + idx / 66, j = 2 + idx % 66;
        int gx = x0 - 3 + i, gy = y0 - 3 + j;
        float v = 0.f;
        if (gx >= 0 && gx < NXY && gy >= 0 && gy < NXY) v = LAPBC(l1, i, j, gx, gy);
        l2[i][j] = v;
    }
    __syncthreads();
#undef LAPBC

    const int l = c % NL3;
    for (int idx = t; idx < 16 * 64; idx += 256) {
        int i = 3 + idx / 64, j = 3 + idx % 64;
        int gx = x0 - 3 + i, gy = y0 - 3 + j;
        if (gx > NIN || gy > NIN) continue;   // interior is 1..511
        float fmm=qs[i-1][j-1], fm0=qs[i-1][j], fmp=qs[i-1][j+1];
        float f0m=qs[i][j-1],                    f0p=qs[i][j+1];
        float fpm=qs[i+1][j-1], fp0=qs[i+1][j], fpp=qs[i+1][j+1];
        float gmm=ps[i-1][j-1], gm0=ps[i-1][j], gmp=ps[i-1][j+1];
        float g0m=ps[i][j-1],   g00=ps[i][j],   g0p=ps[i][j+1];
        float gpm=ps[i+1][j-1], gp0=ps[i+1][j], gpp=ps[i+1][j+1];
        float J1 = (fp0 - fm0) * (g0p - g0m) - (gp0 - gm0) * (f0p - f0m);
        float J2 = fp0 * (gpp - gpm) - fm0 * (gmp - gmm);
        float J3 = f0p * (gpp - gmp) - f0m * (gpm - gmm);
        float J4 = g0p * (fpp - fmp) - g0m * (fpm - fmm);
        float J5 = gp0 * (fpp - fpm) - gm0 * (fmp - fmm);
        float jac = (J1 + J2 - J3 + J4 - J5) * (1.0f / 12.0f);
        float lap3 = l2[i+1][j] + l2[i-1][j] + l2[i][j+1] + l2[i][j-1] - 4.f * l2[i][j];
        float v = JACCf * jac - HYPCf * lap3;
        if (l == 0)       v += wind[(size_t)(gx-1) * NIN + (gy-1)];
        if (l == NL3-1)   v += BFCf * (gp0 + gm0 + g0p + g0m - 4.f * g00);
        kq[off + (size_t)gx * NXY + gy] = v;
    }
}

// ---------------- layer->mode, writes bf16 hi/lo compact 512x512 (pads zeroed) -----------------
__global__ void l2m_kernel(unsigned short* __restrict__ Gh, unsigned short* __restrict__ Gl,
                           const float* __restrict__ kq, const float* __restrict__ Cl2m) {
    int ry = blockIdx.x * blockDim.x + threadIdx.x;
    int rx = blockIdx.y * blockDim.y + threadIdx.y;
    int e = blockIdx.z;
    size_t go = (size_t)(e * NL3) * GLD * GLD + (size_t)rx * GLD + ry;
    if (rx >= NIN || ry >= NIN) {
        for (int i = 0; i < 3; ++i) { Gh[go + (size_t)i*GLD*GLD] = 0; Gl[go + (size_t)i*GLD*GLD] = 0; }
        return;
    }
    size_t base = ((size_t)(e * NL3) * NXY + (rx + 1)) * NXY + (ry + 1);
    float f0 = kq[base];
    float f1 = kq[base + (size_t)NXY*NXY];
    float f2 = kq[base + 2*(size_t)NXY*NXY];
    float v[3];
    v[0] = Cl2m[0]*f0 + Cl2m[1]*f1 + Cl2m[2]*f2;
    v[1] = Cl2m[3]*f0 + Cl2m[4]*f1 + Cl2m[5]*f2;
    v[2] = Cl2m[6]*f0 + Cl2m[7]*f1 + Cl2m[8]*f2;
#pragma unroll
    for (int i = 0; i < 3; ++i) {
        unsigned short hs = f2bf(v[i]);
        Gh[go + (size_t)i*GLD*GLD] = hs;
        Gl[go + (size_t)i*GLD*GLD] = f2bf(v[i] - bf2f(hs));
    }
}

// ---------------- split-bf16 MFMA GEMM (3-product): out = store_T(A * S) -----------------------
// Tile 128(m) x 64(n), BK=64, 4 waves (2x2), 48KB single-buffered LDS, reg-prefetch.
#define SWZ(o) ((o) ^ ((((o) >> 7) & 7) << 4))
__global__ __launch_bounds__(256, 2) void gemm_dst(
    const unsigned short* __restrict__ Ah, const unsigned short* __restrict__ Al,
    const unsigned short* __restrict__ Sh, const unsigned short* __restrict__ Sl,
    unsigned short* __restrict__ Ch, unsigned short* __restrict__ Cl,
    float* __restrict__ Cf, const float* __restrict__ helm)
{
    // byte offsets: Ah @0 (16KB), Al @16384, Bh @32768 (8KB), Bl @40960
    __shared__ __attribute__((aligned(16))) unsigned short lds[24576]; // 48KB
    const int b  = blockIdx.z;
    const int m0 = blockIdx.x << 7;   // 512/128 = 4
    const int n0 = blockIdx.y << 6;   // 512/64  = 8
    const int t  = threadIdx.x;
    const int w  = t >> 6, l = t & 63;
    const int wr = w >> 1, wc = w & 1;
    const int lr = l & 15, g = l >> 4;
    const unsigned short* Abh = Ah + (size_t)b * 262144;
    const unsigned short* Abl = Al + (size_t)b * 262144;

    int soA[4]; size_t agA[4];
#pragma unroll
    for (int u = 0; u < 4; ++u) {
        int o = t*16 + u*4096;
        soA[u] = SWZ(o);
        agA[u] = (size_t)(m0 + (o >> 7)) * 512 + ((o & 127) >> 1);
    }
    int soB[2]; size_t agB[2];
#pragma unroll
    for (int u = 0; u < 2; ++u) {
        int o = t*16 + u*4096;
        soB[u] = SWZ(o);
        agB[u] = (size_t)(n0 + (o >> 7)) * 512 + ((o & 127) >> 1);
    }

    uint4 rah[4], ral[4], rbh[2], rbl[2];
    auto LOAD = [&](int kt) {
#pragma unroll
        for (int u = 0; u < 4; ++u) {
            rah[u] = *(const uint4*)(Abh + agA[u] + kt*64);
            ral[u] = *(const uint4*)(Abl + agA[u] + kt*64);
        }
#pragma unroll
        for (int u = 0; u < 2; ++u) {
            rbh[u] = *(const uint4*)(Sh + agB[u] + kt*64);
            rbl[u] = *(const uint4*)(Sl + agB[u] + kt*64);
        }
    };
    auto STORE = [&]() {
#pragma unroll
        for (int u = 0; u < 4; ++u) {
            *(uint4*)((char*)lds + soA[u])         = rah[u];
            *(uint4*)((char*)lds + 16384 + soA[u]) = ral[u];
        }
#pragma unroll
        for (int u = 0; u < 2; ++u) {
            *(uint4*)((char*)lds + 32768 + soB[u]) = rbh[u];
            *(uint4*)((char*)lds + 40960 + soB[u]) = rbl[u];
        }
    };

    f32x4 acc[4][2] = {};
    int abyte[4], bbyte[2];
#pragma unroll
    for (int i = 0; i < 4; ++i) abyte[i] = (wr*64 + i*16 + lr)*128 + g*16;
#pragma unroll
    for (int j = 0; j < 2; ++j) bbyte[j] = (wc*32 + j*16 + lr)*128 + g*16;

    LOAD(0); STORE(); __syncthreads();
    for (int it = 0; it < 8; ++it) {
        if (it < 7) LOAD(it + 1);
#pragma unroll
        for (int kk = 0; kk < 2; ++kk) {
            bf16x8 fbh[2], fbl[2];
#pragma unroll
            for (int j = 0; j < 2; ++j) {
                int ob = SWZ(bbyte[j] + kk*64);
                fbh[j] = *(const bf16x8*)((const char*)lds + 32768 + ob);
                fbl[j] = *(const bf16x8*)((const char*)lds + 40960 + ob);
            }
#pragma unroll
            for (int i = 0; i < 4; ++i) {
                int oa = SWZ(abyte[i] + kk*64);
                bf16x8 fah = *(const bf16x8*)((const char*)lds + oa);
                bf16x8 fal = *(const bf16x8*)((const char*)lds + 16384 + oa);
#pragma unroll
                for (int j = 0; j < 2; ++j) {
                    acc[i][j] = __builtin_amdgcn_mfma_f32_16x16x32_bf16(fah, fbh[j], acc[i][j], 0, 0, 0);
                    acc[i][j] = __builtin_amdgcn_mfma_f32_16x16x32_bf16(fah, fbl[j], acc[i][j], 0, 0, 0);
                    acc[i][j] = __builtin_amdgcn_mfma_f32_16x16x32_bf16(fal, fbh[j], acc[i][j], 0, 0, 0);
                }
            }
        }
        __syncthreads();
        if (it < 7) { STORE(); __syncthreads(); }
    }

    const int mode = b % NL3;
    const float* hp = helm ? (helm + (size_t)mode * NIN * NIN) : nullptr;
#pragma unroll
    for (int i = 0; i < 4; ++i) {
        int mmb = m0 + wr*64 + i*16 + 4*g;
#pragma unroll
        for (int j = 0; j < 2; ++j) {
            int nn = n0 + wc*32 + j*16 + lr;
            float v[4];
#pragma unroll
            for (int r = 0; r < 4; ++r) v[r] = acc[i][j][r];
            if (hp && nn < NIN) {
#pragma unroll
                for (int r = 0; r < 4; ++r)
                    if (mmb + r < NIN) v[r] /= hp[(size_t)nn*NIN + mmb + r];
            }
            size_t co = (size_t)b*262144 + (size_t)nn*512 + mmb;
            if (Cf) {
                f32x4 vv = {v[0], v[1], v[2], v[3]};
                *(f32x4*)(Cf + co) = vv;
            } else {
                unsigned short hs0 = f2bf(v[0]), hs1 = f2bf(v[1]), hs2 = f2bf(v[2]), hs3 = f2bf(v[3]);
                unsigned short ls0 = f2bf(v[0]-bf2f(hs0)), ls1 = f2bf(v[1]-bf2f(hs1));
                unsigned short ls2 = f2bf(v[2]-bf2f(hs2)), ls3 = f2bf(v[3]-bf2f(hs3));
                unsigned int h01 = (unsigned int)hs0 | ((unsigned int)hs1 << 16);
                unsigned int h23 = (unsigned int)hs2 | ((unsigned int)hs3 << 16);
                unsigned int l01 = (unsigned int)ls0 | ((unsigned int)ls1 << 16);
                unsigned int l23 = (unsigned int)ls2 | ((unsigned int)ls3 << 16);
                *(uint2*)(Ch + co) = make_uint2(h01, h23);
                *(uint2*)(Cl + co) = make_uint2(l01, l23);
            }
        }
    }
}

// ---------------- per-(e,mode<2) partial sums of dp_modes --------------------------------------
__global__ void mean_kernel(float* __restrict__ partial, const float* __restrict__ G) {
    int gy = blockIdx.y;
    int e = gy >> 1, m = gy & 1;
    const float* g = G + (size_t)(e * NL3 + m) * GLD * GLD;
    float s = 0.f;
    for (int idx = blockIdx.x * 256 + threadIdx.x; idx < GLD*GLD; idx += 64 * 256)
        s += g[idx];
    __shared__ float red[256];
    red[threadIdx.x] = s; __syncthreads();
    for (int w = 128; w >= 1; w >>= 1) {
        if (threadIdx.x < w) red[threadIdx.x] += red[threadIdx.x + w];
        __syncthreads();
    }
    if (threadIdx.x == 0) partial[gy * 64 + blockIdx.x] = red[0];
}

__global__ void dalpha_kernel(float* __restrict__ dal, const float* __restrict__ partial,
                              const float* __restrict__ alpha) {
    int t = threadIdx.x;
    if (t >= 8) return;
    int e = t >> 1, i = t & 1;
    float s0 = 0.f, s1 = 0.f;
    for (int bk = 0; bk < 64; ++bk) { s0 += partial[(e*2+0)*64 + bk]; s1 += partial[(e*2+1)*64 + bk]; }
    const float inv = 1.0f / ((float)NXY * (float)NXY);
    dal[t] = alpha[i*2+0] * (s0 * inv) + alpha[i*2+1] * (s1 * inv);
}

// ---------------- mode->layer -------------------------------------------------------------------
__global__ void m2l_kernel(float* __restrict__ kp, const float* __restrict__ G,
                           const float* __restrict__ dal, const float* __restrict__ hom,
                           const float* __restrict__ Cm2l) {
    int y = blockIdx.x * blockDim.x + threadIdx.x;
    int x = blockIdx.y * blockDim.y + threadIdx.y;
    int e = blockIdx.z;
    if (x >= NXY || y >= NXY) return;
    float mv[3];
    bool interior = (x >= 1 && x <= NIN && y >= 1 && y <= NIN);
#pragma unroll
    for (int i = 0; i < 3; ++i)
        mv[i] = interior ? G[(size_t)(e*NL3 + i) * GLD * GLD + (size_t)(x-1) * GLD + (y-1)] : 0.f;
    float h0 = hom[(size_t)x * NXY + y];
    float h1 = hom[(size_t)NXY*NXY + (size_t)x * NXY + y];
    mv[0] += dal[e*2 + 0] * h0;
    mv[1] += dal[e*2 + 1] * h1;
#pragma unroll
    for (int l = 0; l < 3; ++l)
        kp[((size_t)(e*NL3 + l) * NXY + x) * NXY + y] =
            Cm2l[l*3+0]*mv[0] + Cm2l[l*3+1]*mv[1] + Cm2l[l*3+2]*mv[2];
}

// ---------------- boundary dq -------------------------------------------------------------------
__global__ void bound_kernel(float* __restrict__ kq, const float* __restrict__ kp,
                             const float* __restrict__ Amat) {
    int pos = blockIdx.x * 256 + threadIdx.x;
    int e = blockIdx.y;
    if (pos >= 2048) return;
    int x, y, xn, yn;
    if (pos < NIN)            { x = 0;      y = pos + 1;        xn = 1;      yn = y; }
    else if (pos < 2*NIN)     { x = NXY-1;  y = pos - NIN + 1;  xn = NXY-2;  yn = y; }
    else if (pos < 2*NIN+NXY) { x = pos - 2*NIN;       y = 0;      xn = x; yn = 1; }
    else                      { x = pos - (2*NIN+NXY); y = NXY-1;  xn = x; yn = NXY-2; }
    float dpb[3], lpb[3];
#pragma unroll
    for (int j = 0; j < 3; ++j) {
        const float* f = kp + (size_t)(e*NL3 + j) * NXY * NXY;
        float c = f[(size_t)x * NXY + y];
        float nb = f[(size_t)xn * NXY + yn];
        dpb[j] = c;
        lpb[j] = ZFBCf * INVF0DX2f * (nb - c);
    }
#pragma unroll
    for (int l = 0; l < 3; ++l) {
        float v = lpb[l] - (Amat[l*3+0]*dpb[0] + Amat[l*3+1]*dpb[1] + Amat[l*3+2]*dpb[2]);
        kq[((size_t)(e*NL3 + l) * NXY + x) * NXY + y] = v;
    }
}

// ---------------- fused RK4 update: o1 = (acc? o1:x) + c1*dt*k ; o2 = x + c2*dt*k ---------------
__global__ void rk_fused(float4* __restrict__ o1, float4* __restrict__ o2,
                         const float4* __restrict__ x, const float4* __restrict__ k,
                         float c1, float c2, int accumulate,
                         const float* __restrict__ t, int s, long n4) {
    float dt = t[s+1] - t[s];
    float a1 = c1 * dt, a2 = c2 * dt;
    for (long i = (long)blockIdx.x * blockDim.x + threadIdx.x; i < n4;
         i += (long)gridDim.x * blockDim.x) {
        float4 kk = k[i], xx = x[i];
        float4 b0 = accumulate ? o1[i] : xx;
        o1[i] = make_float4(b0.x + a1*kk.x, b0.y + a1*kk.y, b0.z + a1*kk.z, b0.w + a1*kk.w);
        if (o2) o2[i] = make_float4(xx.x + a2*kk.x, xx.y + a2*kk.y, xx.z + a2*kk.z, xx.w + a2*kk.w);
    }
}

__global__ void copy_kernel(float4* __restrict__ out, const float4* __restrict__ in, long n4) {
    for (long i = (long)blockIdx.x * blockDim.x + threadIdx.x; i < n4;
         i += (long)gridDim.x * blockDim.x)
        out[i] = in[i];
}

// ===============================================================================================
extern "C" void kernel_launch(void* const* d_in, const int* in_sizes, int n_in,
                              void* d_out, int out_size, void* d_ws, size_t ws_size,
                              hipStream_t stream) {
    const float* y0    = (const float*)d_in[0];
    const float* tarr  = (const float*)d_in[1];
    const float* Amat  = (const float*)d_in[2];
    const float* Cl2m  = (const float*)d_in[3];
    const float* Cm2l  = (const float*)d_in[4];
    const float* helm  = (const float*)d_in[5];
    const float* alpha = (const float*)d_in[6];
    const float* hom   = (const float*)d_in[7];
    const float* wind  = (const float*)d_in[8];
    float* out = (float*)d_out;
    char* base = (char*)d_ws;

    unsigned short* Sh = (unsigned short*)base;                       // 512 KB
    unsigned short* Sl = (unsigned short*)(base + 512*1024);          // 512 KB
    float* ytmp = (float*)(base + 1024*1024);                         // 2*FS floats
    float* kbuf = ytmp + 2*FS;                                        // 2*FS floats
    char*  REGb = (char*)(kbuf + 2*FS);
    unsigned short* P0h = (unsigned short*)REGb;
    unsigned short* P0l = P0h + GSZ;
    unsigned short* P1h = P0l + GSZ;
    unsigned short* P1l = P1h + GSZ;
    float* R4 = (float*)REGb;                                         // aliases P0h/P0l (safe)
    float* partial = (float*)(REGb + (size_t)2*FS*sizeof(float));
    float* dal = partial + 512;

    const dim3 bSt(64, 4, 1);
    const dim3 gSt4((NXY + 63)/64, (NXY + 3)/4, NE4);
    const dim3 gL2M(8, 128, NE4);
    const dim3 gF(8, 32, NB);          // fused_rhs: 64-col tiles x 16-row tiles x 12 planes
    const dim3 gG(4, 8, NB);           // gemm: 4 m-tiles x 8 n-tiles x 12 batches
    const long n4 = 2*FS/4;

    initS_kernel<<<dim3(2, GLD), 256, 0, stream>>>(Sh, Sl);
    copy_kernel<<<1024, 256, 0, stream>>>((float4*)out, (const float4*)y0, n4);

    auto deriv = [&](const float* y, float* k) {
        const float* q = y;  const float* p = y + FS;
        float* kq = k;       float* kp = k + FS;
        fused_rhs<<<gF, 256, 0, stream>>>(kq, q, p, wind);
        l2m_kernel<<<gL2M, bSt, 0, stream>>>(P0h, P0l, kq, Cl2m);
        gemm_dst<<<gG, 256, 0, stream>>>(P0h, P0l, Sh, Sl, P1h, P1l, nullptr, nullptr);
        gemm_dst<<<gG, 256, 0, stream>>>(P1h, P1l, Sh, Sl, P0h, P0l, nullptr, helm);
        gemm_dst<<<gG, 256, 0, stream>>>(P0h, P0l, Sh, Sl, P1h, P1l, nullptr, nullptr);
        gemm_dst<<<gG, 256, 0, stream>>>(P1h, P1l, Sh, Sl, nullptr, nullptr, R4, nullptr);
        mean_kernel<<<dim3(64, 8), 256, 0, stream>>>(partial, R4);
        dalpha_kernel<<<1, 64, 0, stream>>>(dal, partial, alpha);
        m2l_kernel<<<gSt4, bSt, 0, stream>>>(kp, R4, dal, hom, Cm2l);
        bound_kernel<<<dim3(8, NE4), 256, 0, stream>>>(kq, kp, Amat);
    };

    for (int s = 0; s < NSTEPS; ++s) {
        float* ycur  = out + (size_t)s * 2 * FS;
        float* ynext = out + (size_t)(s + 1) * 2 * FS;
        deriv(ycur, kbuf);
        rk_fused<<<1024, 256, 0, stream>>>((float4*)ynext, (float4*)ytmp, (const float4*)ycur,
                                           (const float4*)kbuf, 1.f/6.f, 0.5f, 0, tarr, s, n4);
        deriv(ytmp, kbuf);
        rk_fused<<<1024, 256, 0, stream>>>((float4*)ynext, (float4*)ytmp, (const float4*)ycur,
                                           (const float4*)kbuf, 2.f/6.f, 0.5f, 1, tarr, s, n4);
        deriv(ytmp, kbuf);
        rk_fused<<<1024, 256, 0, stream>>>((float4*)ynext, (float4*)ytmp, (const float4*)ycur,
                                           (const float4*)kbuf, 2.f/6.f, 1.0f, 1, tarr, s, n4);
        deriv(ytmp, kbuf);
        rk_fused<<<1024, 256, 0, stream>>>((float4*)ynext, nullptr, (const float4*)ycur,
                                           (const float4*)kbuf, 1.f/6.f, 0.f, 1, tarr, s, n4);
    }
}

// Round 5
// 5081.539 us; speedup vs baseline: 1.0163x; 1.0163x over previous
//
#include <hip/hip_runtime.h>
#include <math.h>

#define NXY 513
#define NIN 511
#define NL3 3
#define NE4 4
#define NB 12
#define GLD 512

static constexpr long FS  = (long)NE4 * NL3 * NXY * NXY;   // 3,158,028 floats
static constexpr long GSZ = (long)NB * GLD * GLD;          // 3,145,728 elements
static constexpr int  NSTEPS = 4;

static constexpr double dF0 = 9.375e-05;
static constexpr double dDX = 10000.0;
static constexpr float ZFBCf     = (float)(0.2 / (1.0 + 0.5 * 0.2));
static constexpr float JACCf     = (float)(1.0 / (dF0 * dDX * dDX));
static constexpr float HYPCf     = (float)(2.0e9 / (dF0 * dF0) / (dDX*dDX*dDX*dDX*dDX*dDX));
static constexpr float BFCf      = (float)(2.0 / (2.0 * dF0 * dDX * dDX * (-2900.0)));
static constexpr float INVF0DX2f = (float)(1.0 / ((dF0 * dDX) * (dF0 * dDX)));

typedef short  bf16x8 __attribute__((ext_vector_type(8)));
typedef float  f32x4  __attribute__((ext_vector_type(4)));

__device__ __forceinline__ unsigned short f2bf(float x) {
    unsigned int u = __float_as_uint(x);
    return (unsigned short)((u + 0x7FFFu + ((u >> 16) & 1u)) >> 16);
}
__device__ __forceinline__ float bf2f(unsigned short h) {
    return __uint_as_float(((unsigned int)h) << 16);
}

// ---------------- DST matrix (bf16 hi/lo): S[n][k] = (1/16) sin(pi (n+1)(k+1)/512), zero-padded --
__global__ void initS_kernel(unsigned short* __restrict__ Sh, unsigned short* __restrict__ Sl) {
    int k = blockIdx.x * 256 + threadIdx.x;
    int n = blockIdx.y;
    if (k >= GLD || n >= GLD) return;
    float v = 0.f;
    if (n < NIN && k < NIN) {
        int m = ((n + 1) * (k + 1)) & 1023;
        v = (float)(0.0625 * sin(M_PI * (double)m / 512.0));
    }
    unsigned short hs = f2bf(v);
    Sh[n * GLD + k] = hs;
    Sl[n * GLD + k] = f2bf(v - bf2f(hs));
}

// ---------------- fused lap(lap_bc(lap_bc(p))) + jacobian + wind + friction --------------------
__global__ __launch_bounds__(256) void fused_rhs(
    float* __restrict__ kq, const float* __restrict__ q, const float* __restrict__ p,
    const float* __restrict__ wind)
{
    __shared__ float ps[22][72];
    __shared__ float qs[22][72];
    __shared__ float l1[22][72];
    __shared__ float l2[22][72];
    const int c  = blockIdx.z;
    const int x0 = 1 + blockIdx.y * 16;
    const int y0 = 1 + blockIdx.x * 64;
    const int t  = threadIdx.x;
    const size_t off = (size_t)c * NXY * NXY;
    const float* pp = p + off;
    const float* qp = q + off;

    for (int idx = t; idx < 22 * 70; idx += 256) {
        int i = idx / 70, j = idx % 70;
        int gx = x0 - 3 + i, gy = y0 - 3 + j;
        bool in = (gx >= 0 && gx < NXY && gy >= 0 && gy < NXY);
        size_t go = (size_t)gx * NXY + gy;
        ps[i][j] = in ? pp[go] : 0.f;
        qs[i][j] = in ? qp[go] : 0.f;
    }
    __syncthreads();

#define LAPBC(a, i, j, gx, gy) \
    ((gy) == 0       ? ZFBCf * (a[i][(j)+1] - a[i][j]) : \
     (gy) == NXY-1   ? ZFBCf * (a[i][(j)-1] - a[i][j]) : \
     (gx) == 0       ? ZFBCf * (a[(i)+1][j] - a[i][j]) : \
     (gx) == NXY-1   ? ZFBCf * (a[(i)-1][j] - a[i][j]) : \
     a[(i)+1][j] + a[(i)-1][j] + a[i][(j)+1] + a[i][(j)-1] - 4.f * a[i][j])

    for (int idx = t; idx < 20 * 68; idx += 256) {
        int i = 1 + idx / 68, j = 1 + idx % 68;
        int gx = x0 - 3 + i, gy = y0 - 3 + j;
        float v = 0.f;
        if (gx >= 0 && gx < NXY && gy >= 0 && gy < NXY) v = LAPBC(ps, i, j, gx, gy);
        l1[i][j] = v;
    }
    __syncthreads();

    for (int idx = t; idx < 18 * 66; idx += 256) {
        int i = 2 + idx / 66, j = 2 + idx % 66;
        int gx = x0 - 3 + i, gy = y0 - 3 + j;
        float v = 0.f;
        if (gx >= 0 && gx < NXY && gy >= 0 && gy < NXY) v = LAPBC(l1, i, j, gx, gy);
        l2[i][j] = v;
    }
    __syncthreads();
#undef LAPBC

    const int l = c % NL3;
    for (int idx = t; idx < 16 * 64; idx += 256) {
        int i = 3 + idx / 64, j = 3 + idx % 64;
        int gx = x0 - 3 + i, gy = y0 - 3 + j;
        if (gx > NIN || gy > NIN) continue;
        float fmm=qs[i-1][j-1], fm0=qs[i-1][j], fmp=qs[i-1][j+1];
        float f0m=qs[i][j-1],                    f0p=qs[i][j+1];
        float fpm=qs[i+1][j-1], fp0=qs[i+1][j], fpp=qs[i+1][j+1];
        float gmm=ps[i-1][j-1], gm0=ps[i-1][j], gmp=ps[i-1][j+1];
        float g0m=ps[i][j-1],   g00=ps[i][j],   g0p=ps[i][j+1];
        float gpm=ps[i+1][j-1], gp0=ps[i+1][j], gpp=ps[i+1][j+1];
        float J1 = (fp0 - fm0) * (g0p - g0m) - (gp0 - gm0) * (f0p - f0m);
        float J2 = fp0 * (gpp - gpm) - fm0 * (gmp - gmm);
        float J3 = f0p * (gpp - gmp) - f0m * (gpm - gmm);
        float J4 = g0p * (fpp - fmp) - g0m * (fpm - fmm);
        float J5 = gp0 * (fpp - fpm) - gm0 * (fmp - fmm);
        float jac = (J1 + J2 - J3 + J4 - J5) * (1.0f / 12.0f);
        float lap3 = l2[i+1][j] + l2[i-1][j] + l2[i][j+1] + l2[i][j-1] - 4.f * l2[i][j];
        float v = JACCf * jac - HYPCf * lap3;
        if (l == 0)       v += wind[(size_t)(gx-1) * NIN + (gy-1)];
        if (l == NL3-1)   v += BFCf * (gp0 + gm0 + g0p + g0m - 4.f * g00);
        kq[off + (size_t)gx * NXY + gy] = v;
    }
}

// ---------------- layer->mode, writes bf16 hi/lo compact 512x512 (pads zeroed) -----------------
__global__ void l2m_kernel(unsigned short* __restrict__ Gh, unsigned short* __restrict__ Gl,
                           const float* __restrict__ kq, const float* __restrict__ Cl2m) {
    int ry = blockIdx.x * blockDim.x + threadIdx.x;
    int rx = blockIdx.y * blockDim.y + threadIdx.y;
    int e = blockIdx.z;
    size_t go = (size_t)(e * NL3) * GLD * GLD + (size_t)rx * GLD + ry;
    if (rx >= NIN || ry >= NIN) {
        for (int i = 0; i < 3; ++i) { Gh[go + (size_t)i*GLD*GLD] = 0; Gl[go + (size_t)i*GLD*GLD] = 0; }
        return;
    }
    size_t base = ((size_t)(e * NL3) * NXY + (rx + 1)) * NXY + (ry + 1);
    float f0 = kq[base];
    float f1 = kq[base + (size_t)NXY*NXY];
    float f2 = kq[base + 2*(size_t)NXY*NXY];
    float v[3];
    v[0] = Cl2m[0]*f0 + Cl2m[1]*f1 + Cl2m[2]*f2;
    v[1] = Cl2m[3]*f0 + Cl2m[4]*f1 + Cl2m[5]*f2;
    v[2] = Cl2m[6]*f0 + Cl2m[7]*f1 + Cl2m[8]*f2;
#pragma unroll
    for (int i = 0; i < 3; ++i) {
        unsigned short hs = f2bf(v[i]);
        Gh[go + (size_t)i*GLD*GLD] = hs;
        Gl[go + (size_t)i*GLD*GLD] = f2bf(v[i] - bf2f(hs));
    }
}

// ---------------- split-bf16 MFMA GEMM (3-product): out = store_T(A * S) -----------------------
// Tile 128(m) x 64(n), BK=64, 4 waves (2x2), 48KB LDS; epilogue staged through LDS so all
// global stores are coalesced.
#define SWZ(o) ((o) ^ ((((o) >> 7) & 7) << 4))
#define EPLD 133
__global__ __launch_bounds__(256, 2) void gemm_dst(
    const unsigned short* __restrict__ Ah, const unsigned short* __restrict__ Al,
    const unsigned short* __restrict__ Sh, const unsigned short* __restrict__ Sl,
    unsigned short* __restrict__ Ch, unsigned short* __restrict__ Cl,
    float* __restrict__ Cf, const float* __restrict__ helm)
{
    __shared__ __attribute__((aligned(16))) char ldsraw[49152]; // 48KB
    unsigned short* lds = (unsigned short*)ldsraw;              // main loop tiles
    float* ep = (float*)ldsraw;                                 // epilogue [64][EPLD] (34KB alias)
    const int b  = blockIdx.z;
    const int m0 = blockIdx.x << 7;
    const int n0 = blockIdx.y << 6;
    const int t  = threadIdx.x;
    const int w  = t >> 6, l = t & 63;
    const int wr = w >> 1, wc = w & 1;
    const int lr = l & 15, g = l >> 4;
    const unsigned short* Abh = Ah + (size_t)b * 262144;
    const unsigned short* Abl = Al + (size_t)b * 262144;

    int soA[4]; size_t agA[4];
#pragma unroll
    for (int u = 0; u < 4; ++u) {
        int o = t*16 + u*4096;
        soA[u] = SWZ(o);
        agA[u] = (size_t)(m0 + (o >> 7)) * 512 + ((o & 127) >> 1);
    }
    int soB[2]; size_t agB[2];
#pragma unroll
    for (int u = 0; u < 2; ++u) {
        int o = t*16 + u*4096;
        soB[u] = SWZ(o);
        agB[u] = (size_t)(n0 + (o >> 7)) * 512 + ((o & 127) >> 1);
    }

    uint4 rah[4], ral[4], rbh[2], rbl[2];
    auto LOAD = [&](int kt) {
#pragma unroll
        for (int u = 0; u < 4; ++u) {
            rah[u] = *(const uint4*)(Abh + agA[u] + kt*64);
            ral[u] = *(const uint4*)(Abl + agA[u] + kt*64);
        }
#pragma unroll
        for (int u = 0; u < 2; ++u) {
            rbh[u] = *(const uint4*)(Sh + agB[u] + kt*64);
            rbl[u] = *(const uint4*)(Sl + agB[u] + kt*64);
        }
    };
    auto STORE = [&]() {
#pragma unroll
        for (int u = 0; u < 4; ++u) {
            *(uint4*)((char*)lds + soA[u])         = rah[u];
            *(uint4*)((char*)lds + 16384 + soA[u]) = ral[u];
        }
#pragma unroll
        for (int u = 0; u < 2; ++u) {
            *(uint4*)((char*)lds + 32768 + soB[u]) = rbh[u];
            *(uint4*)((char*)lds + 40960 + soB[u]) = rbl[u];
        }
    };

    f32x4 acc[4][2] = {};
    int abyte[4], bbyte[2];
#pragma unroll
    for (int i = 0; i < 4; ++i) abyte[i] = (wr*64 + i*16 + lr)*128 + g*16;
#pragma unroll
    for (int j = 0; j < 2; ++j) bbyte[j] = (wc*32 + j*16 + lr)*128 + g*16;

    LOAD(0); STORE(); __syncthreads();
    for (int it = 0; it < 8; ++it) {
        if (it < 7) LOAD(it + 1);
#pragma unroll
        for (int kk = 0; kk < 2; ++kk) {
            bf16x8 fbh[2], fbl[2];
#pragma unroll
            for (int j = 0; j < 2; ++j) {
                int ob = SWZ(bbyte[j] + kk*64);
                fbh[j] = *(const bf16x8*)((const char*)lds + 32768 + ob);
                fbl[j] = *(const bf16x8*)((const char*)lds + 40960 + ob);
            }
#pragma unroll
            for (int i = 0; i < 4; ++i) {
                int oa = SWZ(abyte[i] + kk*64);
                bf16x8 fah = *(const bf16x8*)((const char*)lds + oa);
                bf16x8 fal = *(const bf16x8*)((const char*)lds + 16384 + oa);
#pragma unroll
                for (int j = 0; j < 2; ++j) {
                    acc[i][j] = __builtin_amdgcn_mfma_f32_16x16x32_bf16(fah, fbh[j], acc[i][j], 0, 0, 0);
                    acc[i][j] = __builtin_amdgcn_mfma_f32_16x16x32_bf16(fah, fbl[j], acc[i][j], 0, 0, 0);
                    acc[i][j] = __builtin_amdgcn_mfma_f32_16x16x32_bf16(fal, fbh[j], acc[i][j], 0, 0, 0);
                }
            }
        }
        __syncthreads();
        if (it < 7) { STORE(); __syncthreads(); }
    }

    // ---- epilogue: helm divide in-register, stage to LDS, coalesced global stores ----
    const int mode = b % NL3;
    const float* hp = helm ? (helm + (size_t)mode * NIN * NIN) : nullptr;
#pragma unroll
    for (int i = 0; i < 4; ++i) {
        int mml = wr*64 + i*16 + 4*g;            // local col (m dim), 4 consecutive
#pragma unroll
        for (int j = 0; j < 2; ++j) {
            int nnl = wc*32 + j*16 + lr;         // local row (n dim)
            int nn = n0 + nnl;
            float v[4];
#pragma unroll
            for (int r = 0; r < 4; ++r) v[r] = acc[i][j][r];
            if (hp && nn < NIN) {
                int mmb = m0 + mml;
#pragma unroll
                for (int r = 0; r < 4; ++r)
                    if (mmb + r < NIN) v[r] /= hp[(size_t)nn*NIN + mmb + r];
            }
#pragma unroll
            for (int r = 0; r < 4; ++r) ep[nnl*EPLD + mml + r] = v[r];
        }
    }
    __syncthreads();

    // 1024 chunks of 8 floats (64 rows x 16 chunks); thread handles 4 chunks
#pragma unroll
    for (int c = 0; c < 4; ++c) {
        int chunk = t + 256*c;
        int row = chunk >> 4;
        int cb  = (chunk & 15) * 8;
        float v[8];
#pragma unroll
        for (int k = 0; k < 8; ++k) v[k] = ep[row*EPLD + cb + k];
        size_t co = (size_t)b*262144 + (size_t)(n0 + row)*512 + m0 + cb;
        if (Cf) {
            f32x4 v0 = {v[0], v[1], v[2], v[3]};
            f32x4 v1 = {v[4], v[5], v[6], v[7]};
            *(f32x4*)(Cf + co)     = v0;
            *(f32x4*)(Cf + co + 4) = v1;
        } else {
            unsigned int h[4], lo[4];
#pragma unroll
            for (int k = 0; k < 4; ++k) {
                unsigned short h0 = f2bf(v[2*k]), h1 = f2bf(v[2*k+1]);
                unsigned short l0 = f2bf(v[2*k]-bf2f(h0)), l1 = f2bf(v[2*k+1]-bf2f(h1));
                h[k]  = (unsigned int)h0 | ((unsigned int)h1 << 16);
                lo[k] = (unsigned int)l0 | ((unsigned int)l1 << 16);
            }
            *(uint4*)(Ch + co) = make_uint4(h[0], h[1], h[2], h[3]);
            *(uint4*)(Cl + co) = make_uint4(lo[0], lo[1], lo[2], lo[3]);
        }
    }
}

// ---------------- per-(e,mode<2) partial sums of dp_modes --------------------------------------
__global__ void mean_kernel(float* __restrict__ partial, const float* __restrict__ G) {
    int gy = blockIdx.y;
    int e = gy >> 1, m = gy & 1;
    const float* g = G + (size_t)(e * NL3 + m) * GLD * GLD;
    float s = 0.f;
    for (int idx = blockIdx.x * 256 + threadIdx.x; idx < GLD*GLD; idx += 64 * 256)
        s += g[idx];
    __shared__ float red[256];
    red[threadIdx.x] = s; __syncthreads();
    for (int w = 128; w >= 1; w >>= 1) {
        if (threadIdx.x < w) red[threadIdx.x] += red[threadIdx.x + w];
        __syncthreads();
    }
    if (threadIdx.x == 0) partial[gy * 64 + blockIdx.x] = red[0];
}

__global__ void dalpha_kernel(float* __restrict__ dal, const float* __restrict__ partial,
                              const float* __restrict__ alpha) {
    int t = threadIdx.x;
    if (t >= 8) return;
    int e = t >> 1, i = t & 1;
    float s0 = 0.f, s1 = 0.f;
    for (int bk = 0; bk < 64; ++bk) { s0 += partial[(e*2+0)*64 + bk]; s1 += partial[(e*2+1)*64 + bk]; }
    const float inv = 1.0f / ((float)NXY * (float)NXY);
    dal[t] = alpha[i*2+0] * (s0 * inv) + alpha[i*2+1] * (s1 * inv);
}

// ---------------- mode->layer -------------------------------------------------------------------
__global__ void m2l_kernel(float* __restrict__ kp, const float* __restrict__ G,
                           const float* __restrict__ dal, const float* __restrict__ hom,
                           const float* __restrict__ Cm2l) {
    int y = blockIdx.x * blockDim.x + threadIdx.x;
    int x = blockIdx.y * blockDim.y + threadIdx.y;
    int e = blockIdx.z;
    if (x >= NXY || y >= NXY) return;
    float mv[3];
    bool interior = (x >= 1 && x <= NIN && y >= 1 && y <= NIN);
#pragma unroll
    for (int i = 0; i < 3; ++i)
        mv[i] = interior ? G[(size_t)(e*NL3 + i) * GLD * GLD + (size_t)(x-1) * GLD + (y-1)] : 0.f;
    float h0 = hom[(size_t)x * NXY + y];
    float h1 = hom[(size_t)NXY*NXY + (size_t)x * NXY + y];
    mv[0] += dal[e*2 + 0] * h0;
    mv[1] += dal[e*2 + 1] * h1;
#pragma unroll
    for (int l = 0; l < 3; ++l)
        kp[((size_t)(e*NL3 + l) * NXY + x) * NXY + y] =
            Cm2l[l*3+0]*mv[0] + Cm2l[l*3+1]*mv[1] + Cm2l[l*3+2]*mv[2];
}

// ---------------- boundary dq -------------------------------------------------------------------
__global__ void bound_kernel(float* __restrict__ kq, const float* __restrict__ kp,
                             const float* __restrict__ Amat) {
    int pos = blockIdx.x * 256 + threadIdx.x;
    int e = blockIdx.y;
    if (pos >= 2048) return;
    int x, y, xn, yn;
    if (pos < NIN)            { x = 0;      y = pos + 1;        xn = 1;      yn = y; }
    else if (pos < 2*NIN)     { x = NXY-1;  y = pos - NIN + 1;  xn = NXY-2;  yn = y; }
    else if (pos < 2*NIN+NXY) { x = pos - 2*NIN;       y = 0;      xn = x; yn = 1; }
    else                      { x = pos - (2*NIN+NXY); y = NXY-1;  xn = x; yn = NXY-2; }
    float dpb[3], lpb[3];
#pragma unroll
    for (int j = 0; j < 3; ++j) {
        const float* f = kp + (size_t)(e*NL3 + j) * NXY * NXY;
        float c = f[(size_t)x * NXY + y];
        float nb = f[(size_t)xn * NXY + yn];
        dpb[j] = c;
        lpb[j] = ZFBCf * INVF0DX2f * (nb - c);
    }
#pragma unroll
    for (int l = 0; l < 3; ++l) {
        float v = lpb[l] - (Amat[l*3+0]*dpb[0] + Amat[l*3+1]*dpb[1] + Amat[l*3+2]*dpb[2]);
        kq[((size_t)(e*NL3 + l) * NXY + x) * NXY + y] = v;
    }
}

// ---------------- fused RK4 update ---------------------------------------------------------------
__global__ void rk_fused(float4* __restrict__ o1, float4* __restrict__ o2,
                         const float4* __restrict__ x, const float4* __restrict__ k,
                         float c1, float c2, int accumulate,
                         const float* __restrict__ t, int s, long n4) {
    float dt = t[s+1] - t[s];
    float a1 = c1 * dt, a2 = c2 * dt;
    for (long i = (long)blockIdx.x * blockDim.x + threadIdx.x; i < n4;
         i += (long)gridDim.x * blockDim.x) {
        float4 kk = k[i], xx = x[i];
        float4 b0 = accumulate ? o1[i] : xx;
        o1[i] = make_float4(b0.x + a1*kk.x, b0.y + a1*kk.y, b0.z + a1*kk.z, b0.w + a1*kk.w);
        if (o2) o2[i] = make_float4(xx.x + a2*kk.x, xx.y + a2*kk.y, xx.z + a2*kk.z, xx.w + a2*kk.w);
    }
}

__global__ void copy_kernel(float4* __restrict__ out, const float4* __restrict__ in, long n4) {
    for (long i = (long)blockIdx.x * blockDim.x + threadIdx.x; i < n4;
         i += (long)gridDim.x * blockDim.x)
        out[i] = in[i];
}

// ===============================================================================================
extern "C" void kernel_launch(void* const* d_in, const int* in_sizes, int n_in,
                              void* d_out, int out_size, void* d_ws, size_t ws_size,
                              hipStream_t stream) {
    const float* y0    = (const float*)d_in[0];
    const float* tarr  = (const float*)d_in[1];
    const float* Amat  = (const float*)d_in[2];
    const float* Cl2m  = (const float*)d_in[3];
    const float* Cm2l  = (const float*)d_in[4];
    const float* helm  = (const float*)d_in[5];
    const float* alpha = (const float*)d_in[6];
    const float* hom   = (const float*)d_in[7];
    const float* wind  = (const float*)d_in[8];
    float* out = (float*)d_out;
    char* base = (char*)d_ws;

    unsigned short* Sh = (unsigned short*)base;                       // 512 KB
    unsigned short* Sl = (unsigned short*)(base + 512*1024);          // 512 KB
    float* ytmp = (float*)(base + 1024*1024);                         // 2*FS floats
    float* kbuf = ytmp + 2*FS;                                        // 2*FS floats
    char*  REGb = (char*)(kbuf + 2*FS);
    unsigned short* P0h = (unsigned short*)REGb;
    unsigned short* P0l = P0h + GSZ;
    unsigned short* P1h = P0l + GSZ;
    unsigned short* P1l = P1h + GSZ;
    float* R4 = (float*)REGb;                                         // aliases P0h/P0l (safe)
    float* partial = (float*)(REGb + (size_t)2*FS*sizeof(float));
    float* dal = partial + 512;

    const dim3 bSt(64, 4, 1);
    const dim3 gSt4((NXY + 63)/64, (NXY + 3)/4, NE4);
    const dim3 gL2M(8, 128, NE4);
    const dim3 gF(8, 32, NB);
    const dim3 gG(4, 8, NB);
    const long n4 = 2*FS/4;

    initS_kernel<<<dim3(2, GLD), 256, 0, stream>>>(Sh, Sl);
    copy_kernel<<<1024, 256, 0, stream>>>((float4*)out, (const float4*)y0, n4);

    auto deriv = [&](const float* y, float* k) {
        const float* q = y;  const float* p = y + FS;
        float* kq = k;       float* kp = k + FS;
        fused_rhs<<<gF, 256, 0, stream>>>(kq, q, p, wind);
        l2m_kernel<<<gL2M, bSt, 0, stream>>>(P0h, P0l, kq, Cl2m);
        gemm_dst<<<gG, 256, 0, stream>>>(P0h, P0l, Sh, Sl, P1h, P1l, nullptr, nullptr);
        gemm_dst<<<gG, 256, 0, stream>>>(P1h, P1l, Sh, Sl, P0h, P0l, nullptr, helm);
        gemm_dst<<<gG, 256, 0, stream>>>(P0h, P0l, Sh, Sl, P1h, P1l, nullptr, nullptr);
        gemm_dst<<<gG, 256, 0, stream>>>(P1h, P1l, Sh, Sl, nullptr, nullptr, R4, nullptr);
        mean_kernel<<<dim3(64, 8), 256, 0, stream>>>(partial, R4);
        dalpha_kernel<<<1, 64, 0, stream>>>(dal, partial, alpha);
        m2l_kernel<<<gSt4, bSt, 0, stream>>>(kp, R4, dal, hom, Cm2l);
        bound_kernel<<<dim3(8, NE4), 256, 0, stream>>>(kq, kp, Amat);
    };

    for (int s = 0; s < NSTEPS; ++s) {
        float* ycur  = out + (size_t)s * 2 * FS;
        float* ynext = out + (size_t)(s + 1) * 2 * FS;
        deriv(ycur, kbuf);
        rk_fused<<<1024, 256, 0, stream>>>((float4*)ynext, (float4*)ytmp, (const float4*)ycur,
                                           (const float4*)kbuf, 1.f/6.f, 0.5f, 0, tarr, s, n4);
        deriv(ytmp, kbuf);
        rk_fused<<<1024, 256, 0, stream>>>((float4*)ynext, (float4*)ytmp, (const float4*)ycur,
                                           (const float4*)kbuf, 2.f/6.f, 0.5f, 1, tarr, s, n4);
        deriv(ytmp, kbuf);
        rk_fused<<<1024, 256, 0, stream>>>((float4*)ynext, (float4*)ytmp, (const float4*)ycur,
                                           (const float4*)kbuf, 2.f/6.f, 1.0f, 1, tarr, s, n4);
        deriv(ytmp, kbuf);
        rk_fused<<<1024, 256, 0, stream>>>((float4*)ynext, nullptr, (const float4*)ycur,
                                           (const float4*)kbuf, 1.f/6.f, 0.f, 1, tarr, s, n4);
    }
}

// Round 6
// 2282.527 us; speedup vs baseline: 2.2625x; 2.2263x over previous
//
#include <hip/hip_runtime.h>
#include <math.h>

#define NXY 513
#define NIN 511
#define NL3 3
#define NE4 4
#define NB 12
#define GLD 512

static constexpr long FS  = (long)NE4 * NL3 * NXY * NXY;   // 3,158,028 floats
static constexpr long GSZ = (long)NB * GLD * GLD;          // 3,145,728 elements
static constexpr int  NSTEPS = 4;

static constexpr double dF0 = 9.375e-05;
static constexpr double dDX = 10000.0;
static constexpr float ZFBCf     = (float)(0.2 / (1.0 + 0.5 * 0.2));
static constexpr float JACCf     = (float)(1.0 / (dF0 * dDX * dDX));
static constexpr float HYPCf     = (float)(2.0e9 / (dF0 * dF0) / (dDX*dDX*dDX*dDX*dDX*dDX));
static constexpr float BFCf      = (float)(2.0 / (2.0 * dF0 * dDX * dDX * (-2900.0)));
static constexpr float INVF0DX2f = (float)(1.0 / ((dF0 * dDX) * (dF0 * dDX)));

typedef short  bf16x8 __attribute__((ext_vector_type(8)));
typedef float  f32x4  __attribute__((ext_vector_type(4)));
typedef unsigned int u32;
typedef __attribute__((address_space(1))) const u32 GAS;
typedef __attribute__((address_space(3))) u32 LAS;
#define GLDS(gp, lp) __builtin_amdgcn_global_load_lds((GAS*)(gp), (LAS*)(lp), 16, 0, 0)

__device__ __forceinline__ unsigned short f2bf(float x) {
    unsigned int u = __float_as_uint(x);
    return (unsigned short)((u + 0x7FFFu + ((u >> 16) & 1u)) >> 16);
}
__device__ __forceinline__ float bf2f(unsigned short h) {
    return __uint_as_float(((unsigned int)h) << 16);
}

// ---------------- DST matrix (bf16 hi/lo): S[n][k] = (1/16) sin(pi (n+1)(k+1)/512), zero-padded --
__global__ void initS_kernel(unsigned short* __restrict__ Sh, unsigned short* __restrict__ Sl) {
    int k = blockIdx.x * 256 + threadIdx.x;
    int n = blockIdx.y;
    if (k >= GLD || n >= GLD) return;
    float v = 0.f;
    if (n < NIN && k < NIN) {
        int m = ((n + 1) * (k + 1)) & 1023;
        v = (float)(0.0625 * sin(M_PI * (double)m / 512.0));
    }
    unsigned short hs = f2bf(v);
    Sh[n * GLD + k] = hs;
    Sl[n * GLD + k] = f2bf(v - bf2f(hs));
}

// ---------------- fused lap(lap_bc(lap_bc(p))) + jacobian + wind + friction --------------------
__global__ __launch_bounds__(256) void fused_rhs(
    float* __restrict__ kq, const float* __restrict__ q, const float* __restrict__ p,
    const float* __restrict__ wind)
{
    __shared__ float ps[22][72];
    __shared__ float qs[22][72];
    __shared__ float l1[22][72];
    __shared__ float l2[22][72];
    const int c  = blockIdx.z;
    const int x0 = 1 + blockIdx.y * 16;
    const int y0 = 1 + blockIdx.x * 64;
    const int t  = threadIdx.x;
    const size_t off = (size_t)c * NXY * NXY;
    const float* pp = p + off;
    const float* qp = q + off;

    for (int idx = t; idx < 22 * 70; idx += 256) {
        int i = idx / 70, j = idx % 70;
        int gx = x0 - 3 + i, gy = y0 - 3 + j;
        bool in = (gx >= 0 && gx < NXY && gy >= 0 && gy < NXY);
        size_t go = (size_t)gx * NXY + gy;
        ps[i][j] = in ? pp[go] : 0.f;
        qs[i][j] = in ? qp[go] : 0.f;
    }
    __syncthreads();

#define LAPBC(a, i, j, gx, gy) \
    ((gy) == 0       ? ZFBCf * (a[i][(j)+1] - a[i][j]) : \
     (gy) == NXY-1   ? ZFBCf * (a[i][(j)-1] - a[i][j]) : \
     (gx) == 0       ? ZFBCf * (a[(i)+1][j] - a[i][j]) : \
     (gx) == NXY-1   ? ZFBCf * (a[(i)-1][j] - a[i][j]) : \
     a[(i)+1][j] + a[(i)-1][j] + a[i][(j)+1] + a[i][(j)-1] - 4.f * a[i][j])

    for (int idx = t; idx < 20 * 68; idx += 256) {
        int i = 1 + idx / 68, j = 1 + idx % 68;
        int gx = x0 - 3 + i, gy = y0 - 3 + j;
        float v = 0.f;
        if (gx >= 0 && gx < NXY && gy >= 0 && gy < NXY) v = LAPBC(ps, i, j, gx, gy);
        l1[i][j] = v;
    }
    __syncthreads();

    for (int idx = t; idx < 18 * 66; idx += 256) {
        int i = 2 + idx / 66, j = 2 + idx % 66;
        int gx = x0 - 3 + i, gy = y0 - 3 + j;
        float v = 0.f;
        if (gx >= 0 && gx < NXY && gy >= 0 && gy < NXY) v = LAPBC(l1, i, j, gx, gy);
        l2[i][j] = v;
    }
    __syncthreads();
#undef LAPBC

    const int l = c % NL3;
    for (int idx = t; idx < 16 * 64; idx += 256) {
        int i = 3 + idx / 64, j = 3 + idx % 64;
        int gx = x0 - 3 + i, gy = y0 - 3 + j;
        if (gx > NIN || gy > NIN) continue;
        float fmm=qs[i-1][j-1], fm0=qs[i-1][j], fmp=qs[i-1][j+1];
        float f0m=qs[i][j-1],                    f0p=qs[i][j+1];
        float fpm=qs[i+1][j-1], fp0=qs[i+1][j], fpp=qs[i+1][j+1];
        float gmm=ps[i-1][j-1], gm0=ps[i-1][j], gmp=ps[i-1][j+1];
        float g0m=ps[i][j-1],   g00=ps[i][j],   g0p=ps[i][j+1];
        float gpm=ps[i+1][j-1], gp0=ps[i+1][j], gpp=ps[i+1][j+1];
        float J1 = (fp0 - fm0) * (g0p - g0m) - (gp0 - gm0) * (f0p - f0m);
        float J2 = fp0 * (gpp - gpm) - fm0 * (gmp - gmm);
        float J3 = f0p * (gpp - gmp) - f0m * (gpm - gmm);
        float J4 = g0p * (fpp - fmp) - g0m * (fpm - fmm);
        float J5 = gp0 * (fpp - fpm) - gm0 * (fmp - fmm);
        float jac = (J1 + J2 - J3 + J4 - J5) * (1.0f / 12.0f);
        float lap3 = l2[i+1][j] + l2[i-1][j] + l2[i][j+1] + l2[i][j-1] - 4.f * l2[i][j];
        float v = JACCf * jac - HYPCf * lap3;
        if (l == 0)       v += wind[(size_t)(gx-1) * NIN + (gy-1)];
        if (l == NL3-1)   v += BFCf * (gp0 + gm0 + g0p + g0m - 4.f * g00);
        kq[off + (size_t)gx * NXY + gy] = v;
    }
}

// ---------------- layer->mode, writes bf16 hi/lo compact 512x512 (pads zeroed) -----------------
__global__ void l2m_kernel(unsigned short* __restrict__ Gh, unsigned short* __restrict__ Gl,
                           const float* __restrict__ kq, const float* __restrict__ Cl2m) {
    int ry = blockIdx.x * blockDim.x + threadIdx.x;
    int rx = blockIdx.y * blockDim.y + threadIdx.y;
    int e = blockIdx.z;
    size_t go = (size_t)(e * NL3) * GLD * GLD + (size_t)rx * GLD + ry;
    if (rx >= NIN || ry >= NIN) {
        for (int i = 0; i < 3; ++i) { Gh[go + (size_t)i*GLD*GLD] = 0; Gl[go + (size_t)i*GLD*GLD] = 0; }
        return;
    }
    size_t base = ((size_t)(e * NL3) * NXY + (rx + 1)) * NXY + (ry + 1);
    float f0 = kq[base];
    float f1 = kq[base + (size_t)NXY*NXY];
    float f2 = kq[base + 2*(size_t)NXY*NXY];
    float v[3];
    v[0] = Cl2m[0]*f0 + Cl2m[1]*f1 + Cl2m[2]*f2;
    v[1] = Cl2m[3]*f0 + Cl2m[4]*f1 + Cl2m[5]*f2;
    v[2] = Cl2m[6]*f0 + Cl2m[7]*f1 + Cl2m[8]*f2;
#pragma unroll
    for (int i = 0; i < 3; ++i) {
        unsigned short hs = f2bf(v[i]);
        Gh[go + (size_t)i*GLD*GLD] = hs;
        Gl[go + (size_t)i*GLD*GLD] = f2bf(v[i] - bf2f(hs));
    }
}

// ---------------- split-bf16 MFMA GEMM (3-product): out = store_T(A * S) -----------------------
// Tile 128(m) x 64(n), BK=32, 4 waves (2x2), global_load_lds staging (no staging VGPRs),
// double-buffered 2x24KB LDS, flat grid with XCD-affine swizzle (A-sharing blocks on one XCD).
#define EPLD 133
__global__ __launch_bounds__(256, 2) void gemm_dst(
    const unsigned short* __restrict__ Ah, const unsigned short* __restrict__ Al,
    const unsigned short* __restrict__ Sh, const unsigned short* __restrict__ Sl,
    unsigned short* __restrict__ Ch, unsigned short* __restrict__ Cl,
    float* __restrict__ Cf, const float* __restrict__ helm)
{
    __shared__ __attribute__((aligned(16))) char ldsraw[49152]; // 2 bufs x 24KB; epilogue aliases
    float* ep = (float*)ldsraw;
    // flat id -> (n,b,m): ids with same (b,m) differ by 48 (==0 mod 8) -> same XCD L2 holds A slab
    const int id = blockIdx.x;
    const int nblk = id / 48, rr = id - nblk * 48;
    const int b = rr >> 2, mblk = rr & 3;
    const int m0 = mblk << 7, n0 = nblk << 6;
    const int t = threadIdx.x;
    const int wave = t >> 6, lane = t & 63;
    const int wr = wave >> 1, wc = wave & 1;
    const int lr = lane & 15, g = lane >> 4;
    const unsigned short* Abh = Ah + (size_t)b * 262144;
    const unsigned short* Abl = Al + (size_t)b * 262144;

    // staging maps: LDS byte o (linear per plane) <- global element (row=o>>6, colE=(o&63)>>1)
    size_t gA[2]; int ldA[2];
#pragma unroll
    for (int u = 0; u < 2; ++u) {
        int o = wave*1024 + u*4096 + lane*16;
        gA[u] = (size_t)(m0 + (o >> 6)) * 512 + ((o & 63) >> 1);
        ldA[u] = wave*1024 + u*4096;          // wave-uniform LDS base
    }
    int oB = wave*1024 + lane*16;
    size_t gB = (size_t)(n0 + (oB >> 6)) * 512 + ((oB & 63) >> 1);
    int ldB = wave*1024;

    auto STAGE = [&](int buf, int kt) {
        char* bb = ldsraw + buf*24576;
        int ke = kt * 32;
#pragma unroll
        for (int u = 0; u < 2; ++u) {
            GLDS(Abh + gA[u] + ke, bb + ldA[u]);           // A hi @ 0
            GLDS(Abl + gA[u] + ke, bb + 8192 + ldA[u]);    // A lo @ 8K
        }
        GLDS(Sh + gB + ke, bb + 16384 + ldB);              // B hi @ 16K
        GLDS(Sl + gB + ke, bb + 20480 + ldB);              // B lo @ 20K
    };

    f32x4 acc[4][2] = {};
    int abyte[4], bbyte[2];
#pragma unroll
    for (int i = 0; i < 4; ++i) abyte[i] = (wr*64 + i*16 + lr)*64 + g*16;
#pragma unroll
    for (int j = 0; j < 2; ++j) bbyte[j] = 16384 + (wc*32 + j*16 + lr)*64 + g*16;

    STAGE(0, 0);
    __syncthreads();
    for (int it = 0; it < 16; ++it) {
        const int buf = it & 1;
        if (it < 15) STAGE(buf ^ 1, it + 1);
        const char* bb = ldsraw + buf*24576;
        bf16x8 fbh[2], fbl[2];
#pragma unroll
        for (int j = 0; j < 2; ++j) {
            fbh[j] = *(const bf16x8*)(bb + bbyte[j]);
            fbl[j] = *(const bf16x8*)(bb + 4096 + bbyte[j]);
        }
#pragma unroll
        for (int i = 0; i < 4; ++i) {
            bf16x8 fah = *(const bf16x8*)(bb + abyte[i]);
            bf16x8 fal = *(const bf16x8*)(bb + 8192 + abyte[i]);
#pragma unroll
            for (int j = 0; j < 2; ++j) {
                acc[i][j] = __builtin_amdgcn_mfma_f32_16x16x32_bf16(fah, fbh[j], acc[i][j], 0, 0, 0);
                acc[i][j] = __builtin_amdgcn_mfma_f32_16x16x32_bf16(fah, fbl[j], acc[i][j], 0, 0, 0);
                acc[i][j] = __builtin_amdgcn_mfma_f32_16x16x32_bf16(fal, fbh[j], acc[i][j], 0, 0, 0);
            }
        }
        __syncthreads();   // drains prefetch vmcnt; buf^1 ready for next iter
    }

    // ---- epilogue: helm divide in-register, stage to LDS, coalesced global stores ----
    const int mode = b % NL3;
    const float* hp = helm ? (helm + (size_t)mode * NIN * NIN) : nullptr;
#pragma unroll
    for (int i = 0; i < 4; ++i) {
        int mml = wr*64 + i*16 + 4*g;
#pragma unroll
        for (int j = 0; j < 2; ++j) {
            int nnl = wc*32 + j*16 + lr;
            int nn = n0 + nnl;
            float v[4];
#pragma unroll
            for (int r = 0; r < 4; ++r) v[r] = acc[i][j][r];
            if (hp && nn < NIN) {
                int mmb = m0 + mml;
#pragma unroll
                for (int r = 0; r < 4; ++r)
                    if (mmb + r < NIN) v[r] /= hp[(size_t)nn*NIN + mmb + r];
            }
#pragma unroll
            for (int r = 0; r < 4; ++r) ep[nnl*EPLD + mml + r] = v[r];
        }
    }
    __syncthreads();

    // 1024 chunks of 8 floats (64 rows x 16 chunks); thread handles 4 chunks
#pragma unroll
    for (int c = 0; c < 4; ++c) {
        int chunk = t + 256*c;
        int row = chunk >> 4;
        int cb  = (chunk & 15) * 8;
        float v[8];
#pragma unroll
        for (int k = 0; k < 8; ++k) v[k] = ep[row*EPLD + cb + k];
        size_t co = (size_t)b*262144 + (size_t)(n0 + row)*512 + m0 + cb;
        if (Cf) {
            f32x4 v0 = {v[0], v[1], v[2], v[3]};
            f32x4 v1 = {v[4], v[5], v[6], v[7]};
            *(f32x4*)(Cf + co)     = v0;
            *(f32x4*)(Cf + co + 4) = v1;
        } else {
            unsigned int h[4], lo[4];
#pragma unroll
            for (int k = 0; k < 4; ++k) {
                unsigned short h0 = f2bf(v[2*k]), h1 = f2bf(v[2*k+1]);
                unsigned short l0 = f2bf(v[2*k]-bf2f(h0)), l1 = f2bf(v[2*k+1]-bf2f(h1));
                h[k]  = (unsigned int)h0 | ((unsigned int)h1 << 16);
                lo[k] = (unsigned int)l0 | ((unsigned int)l1 << 16);
            }
            *(uint4*)(Ch + co) = make_uint4(h[0], h[1], h[2], h[3]);
            *(uint4*)(Cl + co) = make_uint4(lo[0], lo[1], lo[2], lo[3]);
        }
    }
}

// ---------------- per-(e,mode<2) partial sums of dp_modes --------------------------------------
__global__ void mean_kernel(float* __restrict__ partial, const float* __restrict__ G) {
    int gy = blockIdx.y;
    int e = gy >> 1, m = gy & 1;
    const float* g = G + (size_t)(e * NL3 + m) * GLD * GLD;
    float s = 0.f;
    for (int idx = blockIdx.x * 256 + threadIdx.x; idx < GLD*GLD; idx += 64 * 256)
        s += g[idx];
    __shared__ float red[256];
    red[threadIdx.x] = s; __syncthreads();
    for (int w = 128; w >= 1; w >>= 1) {
        if (threadIdx.x < w) red[threadIdx.x] += red[threadIdx.x + w];
        __syncthreads();
    }
    if (threadIdx.x == 0) partial[gy * 64 + blockIdx.x] = red[0];
}

__global__ void dalpha_kernel(float* __restrict__ dal, const float* __restrict__ partial,
                              const float* __restrict__ alpha) {
    int t = threadIdx.x;
    if (t >= 8) return;
    int e = t >> 1, i = t & 1;
    float s0 = 0.f, s1 = 0.f;
    for (int bk = 0; bk < 64; ++bk) { s0 += partial[(e*2+0)*64 + bk]; s1 += partial[(e*2+1)*64 + bk]; }
    const float inv = 1.0f / ((float)NXY * (float)NXY);
    dal[t] = alpha[i*2+0] * (s0 * inv) + alpha[i*2+1] * (s1 * inv);
}

// ---------------- mode->layer -------------------------------------------------------------------
__global__ void m2l_kernel(float* __restrict__ kp, const float* __restrict__ G,
                           const float* __restrict__ dal, const float* __restrict__ hom,
                           const float* __restrict__ Cm2l) {
    int y = blockIdx.x * blockDim.x + threadIdx.x;
    int x = blockIdx.y * blockDim.y + threadIdx.y;
    int e = blockIdx.z;
    if (x >= NXY || y >= NXY) return;
    float mv[3];
    bool interior = (x >= 1 && x <= NIN && y >= 1 && y <= NIN);
#pragma unroll
    for (int i = 0; i < 3; ++i)
        mv[i] = interior ? G[(size_t)(e*NL3 + i) * GLD * GLD + (size_t)(x-1) * GLD + (y-1)] : 0.f;
    float h0 = hom[(size_t)x * NXY + y];
    float h1 = hom[(size_t)NXY*NXY + (size_t)x * NXY + y];
    mv[0] += dal[e*2 + 0] * h0;
    mv[1] += dal[e*2 + 1] * h1;
#pragma unroll
    for (int l = 0; l < 3; ++l)
        kp[((size_t)(e*NL3 + l) * NXY + x) * NXY + y] =
            Cm2l[l*3+0]*mv[0] + Cm2l[l*3+1]*mv[1] + Cm2l[l*3+2]*mv[2];
}

// ---------------- boundary dq -------------------------------------------------------------------
__global__ void bound_kernel(float* __restrict__ kq, const float* __restrict__ kp,
                             const float* __restrict__ Amat) {
    int pos = blockIdx.x * 256 + threadIdx.x;
    int e = blockIdx.y;
    if (pos >= 2048) return;
    int x, y, xn, yn;
    if (pos < NIN)            { x = 0;      y = pos + 1;        xn = 1;      yn = y; }
    else if (pos < 2*NIN)     { x = NXY-1;  y = pos - NIN + 1;  xn = NXY-2;  yn = y; }
    else if (pos < 2*NIN+NXY) { x = pos - 2*NIN;       y = 0;      xn = x; yn = 1; }
    else                      { x = pos - (2*NIN+NXY); y = NXY-1;  xn = x; yn = NXY-2; }
    float dpb[3], lpb[3];
#pragma unroll
    for (int j = 0; j < 3; ++j) {
        const float* f = kp + (size_t)(e*NL3 + j) * NXY * NXY;
        float c = f[(size_t)x * NXY + y];
        float nb = f[(size_t)xn * NXY + yn];
        dpb[j] = c;
        lpb[j] = ZFBCf * INVF0DX2f * (nb - c);
    }
#pragma unroll
    for (int l = 0; l < 3; ++l) {
        float v = lpb[l] - (Amat[l*3+0]*dpb[0] + Amat[l*3+1]*dpb[1] + Amat[l*3+2]*dpb[2]);
        kq[((size_t)(e*NL3 + l) * NXY + x) * NXY + y] = v;
    }
}

// ---------------- fused RK4 update ---------------------------------------------------------------
__global__ void rk_fused(float4* __restrict__ o1, float4* __restrict__ o2,
                         const float4* __restrict__ x, const float4* __restrict__ k,
                         float c1, float c2, int accumulate,
                         const float* __restrict__ t, int s, long n4) {
    float dt = t[s+1] - t[s];
    float a1 = c1 * dt, a2 = c2 * dt;
    for (long i = (long)blockIdx.x * blockDim.x + threadIdx.x; i < n4;
         i += (long)gridDim.x * blockDim.x) {
        float4 kk = k[i], xx = x[i];
        float4 b0 = accumulate ? o1[i] : xx;
        o1[i] = make_float4(b0.x + a1*kk.x, b0.y + a1*kk.y, b0.z + a1*kk.z, b0.w + a1*kk.w);
        if (o2) o2[i] = make_float4(xx.x + a2*kk.x, xx.y + a2*kk.y, xx.z + a2*kk.z, xx.w + a2*kk.w);
    }
}

__global__ void copy_kernel(float4* __restrict__ out, const float4* __restrict__ in, long n4) {
    for (long i = (long)blockIdx.x * blockDim.x + threadIdx.x; i < n4;
         i += (long)gridDim.x * blockDim.x)
        out[i] = in[i];
}

// ===============================================================================================
extern "C" void kernel_launch(void* const* d_in, const int* in_sizes, int n_in,
                              void* d_out, int out_size, void* d_ws, size_t ws_size,
                              hipStream_t stream) {
    const float* y0    = (const float*)d_in[0];
    const float* tarr  = (const float*)d_in[1];
    const float* Amat  = (const float*)d_in[2];
    const float* Cl2m  = (const float*)d_in[3];
    const float* Cm2l  = (const float*)d_in[4];
    const float* helm  = (const float*)d_in[5];
    const float* alpha = (const float*)d_in[6];
    const float* hom   = (const float*)d_in[7];
    const float* wind  = (const float*)d_in[8];
    float* out = (float*)d_out;
    char* base = (char*)d_ws;

    unsigned short* Sh = (unsigned short*)base;                       // 512 KB
    unsigned short* Sl = (unsigned short*)(base + 512*1024);          // 512 KB
    float* ytmp = (float*)(base + 1024*1024);                         // 2*FS floats
    float* kbuf = ytmp + 2*FS;                                        // 2*FS floats
    char*  REGb = (char*)(kbuf + 2*FS);
    unsigned short* P0h = (unsigned short*)REGb;
    unsigned short* P0l = P0h + GSZ;
    unsigned short* P1h = P0l + GSZ;
    unsigned short* P1l = P1h + GSZ;
    float* R4 = (float*)REGb;                                         // aliases P0h/P0l (safe)
    float* partial = (float*)(REGb + (size_t)2*FS*sizeof(float));
    float* dal = partial + 512;

    const dim3 bSt(64, 4, 1);
    const dim3 gSt4((NXY + 63)/64, (NXY + 3)/4, NE4);
    const dim3 gL2M(8, 128, NE4);
    const dim3 gF(8, 32, NB);
    const dim3 gG(384, 1, 1);
    const long n4 = 2*FS/4;

    initS_kernel<<<dim3(2, GLD), 256, 0, stream>>>(Sh, Sl);
    copy_kernel<<<1024, 256, 0, stream>>>((float4*)out, (const float4*)y0, n4);

    auto deriv = [&](const float* y, float* k) {
        const float* q = y;  const float* p = y + FS;
        float* kq = k;       float* kp = k + FS;
        fused_rhs<<<gF, 256, 0, stream>>>(kq, q, p, wind);
        l2m_kernel<<<gL2M, bSt, 0, stream>>>(P0h, P0l, kq, Cl2m);
        gemm_dst<<<gG, 256, 0, stream>>>(P0h, P0l, Sh, Sl, P1h, P1l, nullptr, nullptr);
        gemm_dst<<<gG, 256, 0, stream>>>(P1h, P1l, Sh, Sl, P0h, P0l, nullptr, helm);
        gemm_dst<<<gG, 256, 0, stream>>>(P0h, P0l, Sh, Sl, P1h, P1l, nullptr, nullptr);
        gemm_dst<<<gG, 256, 0, stream>>>(P1h, P1l, Sh, Sl, nullptr, nullptr, R4, nullptr);
        mean_kernel<<<dim3(64, 8), 256, 0, stream>>>(partial, R4);
        dalpha_kernel<<<1, 64, 0, stream>>>(dal, partial, alpha);
        m2l_kernel<<<gSt4, bSt, 0, stream>>>(kp, R4, dal, hom, Cm2l);
        bound_kernel<<<dim3(8, NE4), 256, 0, stream>>>(kq, kp, Amat);
    };

    for (int s = 0; s < NSTEPS; ++s) {
        float* ycur  = out + (size_t)s * 2 * FS;
        float* ynext = out + (size_t)(s + 1) * 2 * FS;
        deriv(ycur, kbuf);
        rk_fused<<<1024, 256, 0, stream>>>((float4*)ynext, (float4*)ytmp, (const float4*)ycur,
                                           (const float4*)kbuf, 1.f/6.f, 0.5f, 0, tarr, s, n4);
        deriv(ytmp, kbuf);
        rk_fused<<<1024, 256, 0, stream>>>((float4*)ynext, (float4*)ytmp, (const float4*)ycur,
                                           (const float4*)kbuf, 2.f/6.f, 0.5f, 1, tarr, s, n4);
        deriv(ytmp, kbuf);
        rk_fused<<<1024, 256, 0, stream>>>((float4*)ynext, (float4*)ytmp, (const float4*)ycur,
                                           (const float4*)kbuf, 2.f/6.f, 1.0f, 1, tarr, s, n4);
        deriv(ytmp, kbuf);
        rk_fused<<<1024, 256, 0, stream>>>((float4*)ynext, nullptr, (const float4*)ycur,
                                           (const float4*)kbuf, 1.f/6.f, 0.f, 1, tarr, s, n4);
    }
}

// Round 7
// 2264.044 us; speedup vs baseline: 2.2809x; 1.0082x over previous
//
#include <hip/hip_runtime.h>
#include <math.h>

#define NXY 513
#define NIN 511
#define NL3 3
#define NE4 4
#define NB 12
#define GLD 512

static constexpr long FS  = (long)NE4 * NL3 * NXY * NXY;   // 3,158,028 floats
static constexpr long GSZ = (long)NB * GLD * GLD;          // 3,145,728 elements
static constexpr int  NSTEPS = 4;

static constexpr double dF0 = 9.375e-05;
static constexpr double dDX = 10000.0;
static constexpr float ZFBCf     = (float)(0.2 / (1.0 + 0.5 * 0.2));
static constexpr float JACCf     = (float)(1.0 / (dF0 * dDX * dDX));
static constexpr float HYPCf     = (float)(2.0e9 / (dF0 * dF0) / (dDX*dDX*dDX*dDX*dDX*dDX));
static constexpr float BFCf      = (float)(2.0 / (2.0 * dF0 * dDX * dDX * (-2900.0)));
static constexpr float INVF0DX2f = (float)(1.0 / ((dF0 * dDX) * (dF0 * dDX)));

typedef short  bf16x8 __attribute__((ext_vector_type(8)));
typedef float  f32x4  __attribute__((ext_vector_type(4)));
typedef unsigned int u32;
typedef __attribute__((address_space(1))) const u32 GAS;
typedef __attribute__((address_space(3))) u32 LAS;
#define GLDS(gp, lp) __builtin_amdgcn_global_load_lds((GAS*)(gp), (LAS*)(lp), 16, 0, 0)

__device__ __forceinline__ unsigned short f2bf(float x) {
    unsigned int u = __float_as_uint(x);
    return (unsigned short)((u + 0x7FFFu + ((u >> 16) & 1u)) >> 16);
}
__device__ __forceinline__ float bf2f(unsigned short h) {
    return __uint_as_float(((unsigned int)h) << 16);
}

// ---------------- DST matrix (bf16 hi/lo): S[n][k] = (1/16) sin(pi (n+1)(k+1)/512), zero-padded --
__global__ void initS_kernel(unsigned short* __restrict__ Sh, unsigned short* __restrict__ Sl) {
    int k = blockIdx.x * 256 + threadIdx.x;
    int n = blockIdx.y;
    if (k >= GLD || n >= GLD) return;
    float v = 0.f;
    if (n < NIN && k < NIN) {
        int m = ((n + 1) * (k + 1)) & 1023;
        v = (float)(0.0625 * sin(M_PI * (double)m / 512.0));
    }
    unsigned short hs = f2bf(v);
    Sh[n * GLD + k] = hs;
    Sl[n * GLD + k] = f2bf(v - bf2f(hs));
}

// ---------------- fused lap(lap_bc(lap_bc(p))) + jacobian + wind + friction --------------------
__global__ __launch_bounds__(256) void fused_rhs(
    float* __restrict__ kq, const float* __restrict__ q, const float* __restrict__ p,
    const float* __restrict__ wind)
{
    __shared__ float ps[22][72];
    __shared__ float qs[22][72];
    __shared__ float l1[22][72];
    __shared__ float l2[22][72];
    const int c  = blockIdx.z;
    const int x0 = 1 + blockIdx.y * 16;
    const int y0 = 1 + blockIdx.x * 64;
    const int t  = threadIdx.x;
    const size_t off = (size_t)c * NXY * NXY;
    const float* pp = p + off;
    const float* qp = q + off;

    for (int idx = t; idx < 22 * 70; idx += 256) {
        int i = idx / 70, j = idx % 70;
        int gx = x0 - 3 + i, gy = y0 - 3 + j;
        bool in = (gx >= 0 && gx < NXY && gy >= 0 && gy < NXY);
        size_t go = (size_t)gx * NXY + gy;
        ps[i][j] = in ? pp[go] : 0.f;
        qs[i][j] = in ? qp[go] : 0.f;
    }
    __syncthreads();

#define LAPBC(a, i, j, gx, gy) \
    ((gy) == 0       ? ZFBCf * (a[i][(j)+1] - a[i][j]) : \
     (gy) == NXY-1   ? ZFBCf * (a[i][(j)-1] - a[i][j]) : \
     (gx) == 0       ? ZFBCf * (a[(i)+1][j] - a[i][j]) : \
     (gx) == NXY-1   ? ZFBCf * (a[(i)-1][j] - a[i][j]) : \
     a[(i)+1][j] + a[(i)-1][j] + a[i][(j)+1] + a[i][(j)-1] - 4.f * a[i][j])

    for (int idx = t; idx < 20 * 68; idx += 256) {
        int i = 1 + idx / 68, j = 1 + idx % 68;
        int gx = x0 - 3 + i, gy = y0 - 3 + j;
        float v = 0.f;
        if (gx >= 0 && gx < NXY && gy >= 0 && gy < NXY) v = LAPBC(ps, i, j, gx, gy);
        l1[i][j] = v;
    }
    __syncthreads();

    for (int idx = t; idx < 18 * 66; idx += 256) {
        int i = 2 + idx / 66, j = 2 + idx % 66;
        int gx = x0 - 3 + i, gy = y0 - 3 + j;
        float v = 0.f;
        if (gx >= 0 && gx < NXY && gy >= 0 && gy < NXY) v = LAPBC(l1, i, j, gx, gy);
        l2[i][j] = v;
    }
    __syncthreads();
#undef LAPBC

    const int l = c % NL3;
    for (int idx = t; idx < 16 * 64; idx += 256) {
        int i = 3 + idx / 64, j = 3 + idx % 64;
        int gx = x0 - 3 + i, gy = y0 - 3 + j;
        if (gx > NIN || gy > NIN) continue;
        float fmm=qs[i-1][j-1], fm0=qs[i-1][j], fmp=qs[i-1][j+1];
        float f0m=qs[i][j-1],                    f0p=qs[i][j+1];
        float fpm=qs[i+1][j-1], fp0=qs[i+1][j], fpp=qs[i+1][j+1];
        float gmm=ps[i-1][j-1], gm0=ps[i-1][j], gmp=ps[i-1][j+1];
        float g0m=ps[i][j-1],   g00=ps[i][j],   g0p=ps[i][j+1];
        float gpm=ps[i+1][j-1], gp0=ps[i+1][j], gpp=ps[i+1][j+1];
        float J1 = (fp0 - fm0) * (g0p - g0m) - (gp0 - gm0) * (f0p - f0m);
        float J2 = fp0 * (gpp - gpm) - fm0 * (gmp - gmm);
        float J3 = f0p * (gpp - gmp) - f0m * (gpm - gmm);
        float J4 = g0p * (fpp - fmp) - g0m * (fpm - fmm);
        float J5 = gp0 * (fpp - fpm) - gm0 * (fmp - fmm);
        float jac = (J1 + J2 - J3 + J4 - J5) * (1.0f / 12.0f);
        float lap3 = l2[i+1][j] + l2[i-1][j] + l2[i][j+1] + l2[i][j-1] - 4.f * l2[i][j];
        float v = JACCf * jac - HYPCf * lap3;
        if (l == 0)       v += wind[(size_t)(gx-1) * NIN + (gy-1)];
        if (l == NL3-1)   v += BFCf * (gp0 + gm0 + g0p + g0m - 4.f * g00);
        kq[off + (size_t)gx * NXY + gy] = v;
    }
}

// ---------------- layer->mode, writes bf16 hi/lo compact 512x512 (pads zeroed) -----------------
__global__ void l2m_kernel(unsigned short* __restrict__ Gh, unsigned short* __restrict__ Gl,
                           const float* __restrict__ kq, const float* __restrict__ Cl2m) {
    int ry = blockIdx.x * blockDim.x + threadIdx.x;
    int rx = blockIdx.y * blockDim.y + threadIdx.y;
    int e = blockIdx.z;
    size_t go = (size_t)(e * NL3) * GLD * GLD + (size_t)rx * GLD + ry;
    if (rx >= NIN || ry >= NIN) {
        for (int i = 0; i < 3; ++i) { Gh[go + (size_t)i*GLD*GLD] = 0; Gl[go + (size_t)i*GLD*GLD] = 0; }
        return;
    }
    size_t base = ((size_t)(e * NL3) * NXY + (rx + 1)) * NXY + (ry + 1);
    float f0 = kq[base];
    float f1 = kq[base + (size_t)NXY*NXY];
    float f2 = kq[base + 2*(size_t)NXY*NXY];
    float v[3];
    v[0] = Cl2m[0]*f0 + Cl2m[1]*f1 + Cl2m[2]*f2;
    v[1] = Cl2m[3]*f0 + Cl2m[4]*f1 + Cl2m[5]*f2;
    v[2] = Cl2m[6]*f0 + Cl2m[7]*f1 + Cl2m[8]*f2;
#pragma unroll
    for (int i = 0; i < 3; ++i) {
        unsigned short hs = f2bf(v[i]);
        Gh[go + (size_t)i*GLD*GLD] = hs;
        Gl[go + (size_t)i*GLD*GLD] = f2bf(v[i] - bf2f(hs));
    }
}

// ---------------- split-bf16 MFMA GEMM (3-product): out = store_T(A * S) -----------------------
// Tile 64x64, BK=32, grid 768 (3 blocks/CU), global_load_lds with pre-swizzled source,
// double-buffered 2x16KB LDS, XCD-affine flat grid, LDS-staged coalesced epilogue.
#define EPLD 68
__global__ __launch_bounds__(256, 3) void gemm_dst(
    const unsigned short* __restrict__ Ah, const unsigned short* __restrict__ Al,
    const unsigned short* __restrict__ Sh, const unsigned short* __restrict__ Sl,
    unsigned short* __restrict__ Ch, unsigned short* __restrict__ Cl,
    float* __restrict__ Cf, const float* __restrict__ helm)
{
    __shared__ __attribute__((aligned(16))) char ldsraw[32768]; // 2 bufs x 16KB; epilogue aliases
    float* ep = (float*)ldsraw;                                 // [64][EPLD] floats (17.4KB)
    // flat id -> (nblk, b, mblk); same A slab => ids differ by 96 (0 mod 8) => same XCD
    const int id = blockIdx.x;
    const int nblk = id / 96, rr = id - nblk * 96;
    const int b = rr >> 3, mblk = rr & 7;
    const int m0 = mblk << 6, n0 = nblk << 6;
    const int t = threadIdx.x;
    const int wave = t >> 6, lane = t & 63;
    const int wr = wave >> 1, wc = wave & 1;
    const int lr = lane & 15, g = lane >> 4;
    const unsigned short* Abh = Ah + (size_t)b * 262144;
    const unsigned short* Abl = Al + (size_t)b * 262144;

    // LDS plane layout: linear [64 rows][32 cols] bf16 (64B/row), rows = tile m (or n) index.
    // Swizzle: LDS 16B-slot s of row r holds global col16 (s ^ ((r>>1)&3)).
    const int srow = t >> 2;
    const int scol = ((t & 3) ^ ((srow >> 1) & 3)) * 8;   // element col within 32-wide k window
    const size_t gAe = (size_t)(m0 + srow) * 512 + scol;
    const size_t gBe = (size_t)(n0 + srow) * 512 + scol;
    const int ldbase = wave * 1024;                        // wave-uniform LDS base per plane

    auto STAGE = [&](int buf, int kt) {
        char* bb = ldsraw + buf * 16384;
        int ke = kt * 32;
        GLDS(Abh + gAe + ke, bb + ldbase);                 // A hi @ 0
        GLDS(Abl + gAe + ke, bb + 4096 + ldbase);          // A lo @ 4K
        GLDS(Sh  + gBe + ke, bb + 8192 + ldbase);          // B hi @ 8K
        GLDS(Sl  + gBe + ke, bb + 12288 + ldbase);         // B lo @ 12K
    };

    f32x4 acc[2][2] = {};
    int abyte[2], bbyte[2];
#pragma unroll
    for (int i = 0; i < 2; ++i) {
        int ar = wr*32 + i*16 + lr;
        abyte[i] = ar*64 + ((g ^ ((ar >> 1) & 3)) * 16);
    }
#pragma unroll
    for (int j = 0; j < 2; ++j) {
        int br = wc*32 + j*16 + lr;
        bbyte[j] = 8192 + br*64 + ((g ^ ((br >> 1) & 3)) * 16);
    }

    STAGE(0, 0);
    __syncthreads();
    for (int it = 0; it < 16; ++it) {
        const int buf = it & 1;
        if (it < 15) STAGE(buf ^ 1, it + 1);
        const char* bb = ldsraw + buf * 16384;
        bf16x8 fbh[2], fbl[2];
#pragma unroll
        for (int j = 0; j < 2; ++j) {
            fbh[j] = *(const bf16x8*)(bb + bbyte[j]);
            fbl[j] = *(const bf16x8*)(bb + 4096 + bbyte[j]);
        }
#pragma unroll
        for (int i = 0; i < 2; ++i) {
            bf16x8 fah = *(const bf16x8*)(bb + abyte[i]);
            bf16x8 fal = *(const bf16x8*)(bb + 4096 + abyte[i]);
#pragma unroll
            for (int j = 0; j < 2; ++j) {
                acc[i][j] = __builtin_amdgcn_mfma_f32_16x16x32_bf16(fah, fbh[j], acc[i][j], 0, 0, 0);
                acc[i][j] = __builtin_amdgcn_mfma_f32_16x16x32_bf16(fah, fbl[j], acc[i][j], 0, 0, 0);
                acc[i][j] = __builtin_amdgcn_mfma_f32_16x16x32_bf16(fal, fbh[j], acc[i][j], 0, 0, 0);
            }
        }
        __syncthreads();   // drains prefetch vmcnt; buf^1 ready for next iter
    }

    // ---- epilogue: helm divide in-register, stage to LDS, coalesced global stores ----
    const int mode = b % NL3;
    const float* hp = helm ? (helm + (size_t)mode * NIN * NIN) : nullptr;
#pragma unroll
    for (int i = 0; i < 2; ++i) {
        int mml = wr*32 + i*16 + 4*g;
#pragma unroll
        for (int j = 0; j < 2; ++j) {
            int nnl = wc*32 + j*16 + lr;
            int nn = n0 + nnl;
            float v[4];
#pragma unroll
            for (int r = 0; r < 4; ++r) v[r] = acc[i][j][r];
            if (hp && nn < NIN) {
                int mmb = m0 + mml;
#pragma unroll
                for (int r = 0; r < 4; ++r)
                    if (mmb + r < NIN) v[r] /= hp[(size_t)nn*NIN + mmb + r];
            }
#pragma unroll
            for (int r = 0; r < 4; ++r) ep[nnl*EPLD + mml + r] = v[r];
        }
    }
    __syncthreads();

    // 512 chunks of 8 floats (64 rows x 8 chunks); thread handles 2 chunks
#pragma unroll
    for (int c = 0; c < 2; ++c) {
        int chunk = t + 256*c;
        int row = chunk >> 3;
        int cb  = (chunk & 7) * 8;
        float v[8];
#pragma unroll
        for (int k = 0; k < 8; ++k) v[k] = ep[row*EPLD + cb + k];
        size_t co = (size_t)b*262144 + (size_t)(n0 + row)*512 + m0 + cb;
        if (Cf) {
            f32x4 v0 = {v[0], v[1], v[2], v[3]};
            f32x4 v1 = {v[4], v[5], v[6], v[7]};
            *(f32x4*)(Cf + co)     = v0;
            *(f32x4*)(Cf + co + 4) = v1;
        } else {
            unsigned int h[4], lo[4];
#pragma unroll
            for (int k = 0; k < 4; ++k) {
                unsigned short h0 = f2bf(v[2*k]), h1 = f2bf(v[2*k+1]);
                unsigned short l0 = f2bf(v[2*k]-bf2f(h0)), l1 = f2bf(v[2*k+1]-bf2f(h1));
                h[k]  = (unsigned int)h0 | ((unsigned int)h1 << 16);
                lo[k] = (unsigned int)l0 | ((unsigned int)l1 << 16);
            }
            *(uint4*)(Ch + co) = make_uint4(h[0], h[1], h[2], h[3]);
            *(uint4*)(Cl + co) = make_uint4(lo[0], lo[1], lo[2], lo[3]);
        }
    }
}

// ---------------- per-(e,mode<2) partial sums of dp_modes --------------------------------------
__global__ void mean_kernel(float* __restrict__ partial, const float* __restrict__ G) {
    int gy = blockIdx.y;
    int e = gy >> 1, m = gy & 1;
    const float* g = G + (size_t)(e * NL3 + m) * GLD * GLD;
    float s = 0.f;
    for (int idx = blockIdx.x * 256 + threadIdx.x; idx < GLD*GLD; idx += 64 * 256)
        s += g[idx];
    __shared__ float red[256];
    red[threadIdx.x] = s; __syncthreads();
    for (int w = 128; w >= 1; w >>= 1) {
        if (threadIdx.x < w) red[threadIdx.x] += red[threadIdx.x + w];
        __syncthreads();
    }
    if (threadIdx.x == 0) partial[gy * 64 + blockIdx.x] = red[0];
}

__global__ void dalpha_kernel(float* __restrict__ dal, const float* __restrict__ partial,
                              const float* __restrict__ alpha) {
    int t = threadIdx.x;
    if (t >= 8) return;
    int e = t >> 1, i = t & 1;
    float s0 = 0.f, s1 = 0.f;
    for (int bk = 0; bk < 64; ++bk) { s0 += partial[(e*2+0)*64 + bk]; s1 += partial[(e*2+1)*64 + bk]; }
    const float inv = 1.0f / ((float)NXY * (float)NXY);
    dal[t] = alpha[i*2+0] * (s0 * inv) + alpha[i*2+1] * (s1 * inv);
}

// ---------------- mode->layer -------------------------------------------------------------------
__global__ void m2l_kernel(float* __restrict__ kp, const float* __restrict__ G,
                           const float* __restrict__ dal, const float* __restrict__ hom,
                           const float* __restrict__ Cm2l) {
    int y = blockIdx.x * blockDim.x + threadIdx.x;
    int x = blockIdx.y * blockDim.y + threadIdx.y;
    int e = blockIdx.z;
    if (x >= NXY || y >= NXY) return;
    float mv[3];
    bool interior = (x >= 1 && x <= NIN && y >= 1 && y <= NIN);
#pragma unroll
    for (int i = 0; i < 3; ++i)
        mv[i] = interior ? G[(size_t)(e*NL3 + i) * GLD * GLD + (size_t)(x-1) * GLD + (y-1)] : 0.f;
    float h0 = hom[(size_t)x * NXY + y];
    float h1 = hom[(size_t)NXY*NXY + (size_t)x * NXY + y];
    mv[0] += dal[e*2 + 0] * h0;
    mv[1] += dal[e*2 + 1] * h1;
#pragma unroll
    for (int l = 0; l < 3; ++l)
        kp[((size_t)(e*NL3 + l) * NXY + x) * NXY + y] =
            Cm2l[l*3+0]*mv[0] + Cm2l[l*3+1]*mv[1] + Cm2l[l*3+2]*mv[2];
}

// ---------------- boundary dq -------------------------------------------------------------------
__global__ void bound_kernel(float* __restrict__ kq, const float* __restrict__ kp,
                             const float* __restrict__ Amat) {
    int pos = blockIdx.x * 256 + threadIdx.x;
    int e = blockIdx.y;
    if (pos >= 2048) return;
    int x, y, xn, yn;
    if (pos < NIN)            { x = 0;      y = pos + 1;        xn = 1;      yn = y; }
    else if (pos < 2*NIN)     { x = NXY-1;  y = pos - NIN + 1;  xn = NXY-2;  yn = y; }
    else if (pos < 2*NIN+NXY) { x = pos - 2*NIN;       y = 0;      xn = x; yn = 1; }
    else                      { x = pos - (2*NIN+NXY); y = NXY-1;  xn = x; yn = NXY-2; }
    float dpb[3], lpb[3];
#pragma unroll
    for (int j = 0; j < 3; ++j) {
        const float* f = kp + (size_t)(e*NL3 + j) * NXY * NXY;
        float c = f[(size_t)x * NXY + y];
        float nb = f[(size_t)xn * NXY + yn];
        dpb[j] = c;
        lpb[j] = ZFBCf * INVF0DX2f * (nb - c);
    }
#pragma unroll
    for (int l = 0; l < 3; ++l) {
        float v = lpb[l] - (Amat[l*3+0]*dpb[0] + Amat[l*3+1]*dpb[1] + Amat[l*3+2]*dpb[2]);
        kq[((size_t)(e*NL3 + l) * NXY + x) * NXY + y] = v;
    }
}

// ---------------- fused RK4 update ---------------------------------------------------------------
__global__ void rk_fused(float4* __restrict__ o1, float4* __restrict__ o2,
                         const float4* __restrict__ x, const float4* __restrict__ k,
                         float c1, float c2, int accumulate,
                         const float* __restrict__ t, int s, long n4) {
    float dt = t[s+1] - t[s];
    float a1 = c1 * dt, a2 = c2 * dt;
    for (long i = (long)blockIdx.x * blockDim.x + threadIdx.x; i < n4;
         i += (long)gridDim.x * blockDim.x) {
        float4 kk = k[i], xx = x[i];
        float4 b0 = accumulate ? o1[i] : xx;
        o1[i] = make_float4(b0.x + a1*kk.x, b0.y + a1*kk.y, b0.z + a1*kk.z, b0.w + a1*kk.w);
        if (o2) o2[i] = make_float4(xx.x + a2*kk.x, xx.y + a2*kk.y, xx.z + a2*kk.z, xx.w + a2*kk.w);
    }
}

__global__ void copy_kernel(float4* __restrict__ out, const float4* __restrict__ in, long n4) {
    for (long i = (long)blockIdx.x * blockDim.x + threadIdx.x; i < n4;
         i += (long)gridDim.x * blockDim.x)
        out[i] = in[i];
}

// ===============================================================================================
extern "C" void kernel_launch(void* const* d_in, const int* in_sizes, int n_in,
                              void* d_out, int out_size, void* d_ws, size_t ws_size,
                              hipStream_t stream) {
    const float* y0    = (const float*)d_in[0];
    const float* tarr  = (const float*)d_in[1];
    const float* Amat  = (const float*)d_in[2];
    const float* Cl2m  = (const float*)d_in[3];
    const float* Cm2l  = (const float*)d_in[4];
    const float* helm  = (const float*)d_in[5];
    const float* alpha = (const float*)d_in[6];
    const float* hom   = (const float*)d_in[7];
    const float* wind  = (const float*)d_in[8];
    float* out = (float*)d_out;
    char* base = (char*)d_ws;

    unsigned short* Sh = (unsigned short*)base;                       // 512 KB
    unsigned short* Sl = (unsigned short*)(base + 512*1024);          // 512 KB
    float* ytmp = (float*)(base + 1024*1024);                         // 2*FS floats
    float* kbuf = ytmp + 2*FS;                                        // 2*FS floats
    char*  REGb = (char*)(kbuf + 2*FS);
    unsigned short* P0h = (unsigned short*)REGb;
    unsigned short* P0l = P0h + GSZ;
    unsigned short* P1h = P0l + GSZ;
    unsigned short* P1l = P1h + GSZ;
    float* R4 = (float*)REGb;                                         // aliases P0h/P0l (safe)
    float* partial = (float*)(REGb + (size_t)2*FS*sizeof(float));
    float* dal = partial + 512;

    const dim3 bSt(64, 4, 1);
    const dim3 gSt4((NXY + 63)/64, (NXY + 3)/4, NE4);
    const dim3 gL2M(8, 128, NE4);
    const dim3 gF(8, 32, NB);
    const dim3 gG(768, 1, 1);
    const long n4 = 2*FS/4;

    initS_kernel<<<dim3(2, GLD), 256, 0, stream>>>(Sh, Sl);
    copy_kernel<<<1024, 256, 0, stream>>>((float4*)out, (const float4*)y0, n4);

    auto deriv = [&](const float* y, float* k) {
        const float* q = y;  const float* p = y + FS;
        float* kq = k;       float* kp = k + FS;
        fused_rhs<<<gF, 256, 0, stream>>>(kq, q, p, wind);
        l2m_kernel<<<gL2M, bSt, 0, stream>>>(P0h, P0l, kq, Cl2m);
        gemm_dst<<<gG, 256, 0, stream>>>(P0h, P0l, Sh, Sl, P1h, P1l, nullptr, nullptr);
        gemm_dst<<<gG, 256, 0, stream>>>(P1h, P1l, Sh, Sl, P0h, P0l, nullptr, helm);
        gemm_dst<<<gG, 256, 0, stream>>>(P0h, P0l, Sh, Sl, P1h, P1l, nullptr, nullptr);
        gemm_dst<<<gG, 256, 0, stream>>>(P1h, P1l, Sh, Sl, nullptr, nullptr, R4, nullptr);
        mean_kernel<<<dim3(64, 8), 256, 0, stream>>>(partial, R4);
        dalpha_kernel<<<1, 64, 0, stream>>>(dal, partial, alpha);
        m2l_kernel<<<gSt4, bSt, 0, stream>>>(kp, R4, dal, hom, Cm2l);
        bound_kernel<<<dim3(8, NE4), 256, 0, stream>>>(kq, kp, Amat);
    };

    for (int s = 0; s < NSTEPS; ++s) {
        float* ycur  = out + (size_t)s * 2 * FS;
        float* ynext = out + (size_t)(s + 1) * 2 * FS;
        deriv(ycur, kbuf);
        rk_fused<<<1024, 256, 0, stream>>>((float4*)ynext, (float4*)ytmp, (const float4*)ycur,
                                           (const float4*)kbuf, 1.f/6.f, 0.5f, 0, tarr, s, n4);
        deriv(ytmp, kbuf);
        rk_fused<<<1024, 256, 0, stream>>>((float4*)ynext, (float4*)ytmp, (const float4*)ycur,
                                           (const float4*)kbuf, 2.f/6.f, 0.5f, 1, tarr, s, n4);
        deriv(ytmp, kbuf);
        rk_fused<<<1024, 256, 0, stream>>>((float4*)ynext, (float4*)ytmp, (const float4*)ycur,
                                           (const float4*)kbuf, 2.f/6.f, 1.0f, 1, tarr, s, n4);
        deriv(ytmp, kbuf);
        rk_fused<<<1024, 256, 0, stream>>>((float4*)ynext, nullptr, (const float4*)ycur,
                                           (const float4*)kbuf, 1.f/6.f, 0.f, 1, tarr, s, n4);
    }
}